// Round 9
// baseline (255.589 us; speedup 1.0000x reference)
//
#include <hip/hip_runtime.h>
#include <hip/hip_bf16.h>
#include <stdint.h>

// DispersiveLoss: B=1024 rows, D=65536.
// R9: B-operand direct from L2 into registers (2-deep: bbE/bbO sets),
// LDS stages A only (64 KB, traffic 256->160 KB/K-tile: LDS pipe was
// co-saturated with MFMA at R7/R8's 34% MfmaUtil). Decomposition (250
// blocks = 10 upper-tri 256^2 tiles x 25 K-chunks, XCD-grouped) and the
// 4-phase counted-vmcnt schedule otherwise as R8.

#define NROWS 1024
#define KDIM  65536
#define BK    64
#define NCHUNK 25         // K-chunks per tile
#define CHUNK0 41         // K-tiles per chunk (last chunk: 40)
#define PARTN  250        // 10 tiles * 25 chunks

typedef __attribute__((ext_vector_type(8))) short  s16x8;
typedef __attribute__((ext_vector_type(4))) float  f32x4;

#define AS1 __attribute__((address_space(1)))
#define AS3 __attribute__((address_space(3)))

__device__ __forceinline__ ushort f2bf(float f) {
  uint32_t u = __float_as_uint(f);
  return (ushort)((u + 0x7fffu + ((u >> 16) & 1u)) >> 16);  // RNE bf16
}

// ---- fused: row sum-of-squares -> inv_norm, plus raw fp32 -> bf16 cast ----
__global__ void k_prep(const float* __restrict__ z, ushort* __restrict__ zb,
                       float* __restrict__ inv_norm) {
  const int row = blockIdx.x;
  const float4* zr = (const float4*)(z + (size_t)row * KDIM);
  ushort* br = zb + (size_t)row * KDIM;
  float ss = 0.f;
  for (int i = threadIdx.x; i < KDIM / 4; i += blockDim.x) {
    const float4 v = zr[i];
    ss += v.x * v.x + v.y * v.y + v.z * v.z + v.w * v.w;
    ushort4 o;
    o.x = f2bf(v.x); o.y = f2bf(v.y); o.z = f2bf(v.z); o.w = f2bf(v.w);
    ((ushort4*)br)[i] = o;
  }
  for (int off = 32; off; off >>= 1) ss += __shfl_down(ss, off, 64);
  __shared__ float part[4];
  const int lane = threadIdx.x & 63, w = threadIdx.x >> 6;
  if (lane == 0) part[w] = ss;
  __syncthreads();
  if (threadIdx.x == 0) {
    const float t = part[0] + part[1] + part[2] + part[3];
    inv_norm[row] = 1.f / fmaxf(sqrtf(t), 1e-12f);
  }
}

// ---- 256^2 Gram: A in LDS (2x32KB dbuf, 3-bit XOR swizzle), B in VGPRs ----
__global__
__attribute__((amdgpu_flat_work_group_size(512, 512), amdgpu_waves_per_eu(2, 2)))
void k_gram8(const ushort* __restrict__ zb, float* __restrict__ pbuf) {
  extern __shared__ char smem[];
  const int tid  = threadIdx.x;
  const int lane = tid & 63;
  const int wid  = tid >> 6;
  const int wr   = wid >> 2;     // 0..1  (M half)
  const int wc   = wid & 3;      // 0..3  (N quarter)

  // bijective XCD swizzle inverse (n=250, q=31, r=2)
  const int d   = blockIdx.x;
  const int xcd = d & 7, idx = d >> 3;
  const int l   = (xcd < 2) ? xcd * 32 + idx : 64 + (xcd - 2) * 31 + idx;
  const int kc   = l / 10;        // 0..24
  const int tile = l - kc * 10;   // 0..9
  const int kts  = kc * CHUNK0;
  const int cnt  = (kc == NCHUNK - 1) ? 40 : CHUNK0;
  const int pidx = tile * NCHUNK + kc;

  const int tm = (tile < 4) ? 0 : (tile < 7) ? 1 : (tile < 9) ? 2 : 3;
  const int tbase = 4 * tm - ((tm * (tm - 1)) >> 1);
  const int tn = tile - tbase + tm;

  // A staging per-thread constant (pre-swizzled source; linear LDS dest)
  const uint32_t Pt   = (uint32_t)tid * 16u;
  const uint32_t Lt   = Pt ^ (((Pt >> 7) & 7u) << 4);
  const uint32_t vOff = (Lt >> 7) * (uint32_t)(KDIM * 2) + (Lt & 127u);

  // A ds-read per-thread constant
  const uint32_t laneRB  = (uint32_t)(lane & 15) * 128u + (uint32_t)(lane >> 4) * 16u;
  const uint32_t laneSwz = laneRB ^ (((uint32_t)lane & 7u) << 4);

  const char* zbC = (const char*)zb;

  // A panel row-byte bases (halves)
  const uint32_t gA0 = (uint32_t)(tm * 256) * (uint32_t)(KDIM * 2);
  const uint32_t gA1 = gA0 + 128u * (uint32_t)(KDIM * 2);

  // B per-lane global byte offsets: row = tn*256 + (wc>>1)*128 + (wc&1)*64
  //                                      + ni*16 + (lane&15); col-chunk = lane>>4
  const uint32_t rowB0 = (uint32_t)(tn * 256 + (wc >> 1) * 128 + (wc & 1) * 64 + (lane & 15));
  uint32_t bOff[4];
#pragma unroll
  for (int n = 0; n < 4; n++)
    bOff[n] = (rowB0 + (uint32_t)n * 16u) * (uint32_t)(KDIM * 2)
            + ((uint32_t)(lane >> 4)) * 16u + (uint32_t)kts * 128u;

  // stage one 128x64 A half-tile (16 KB): 2 x global_load_lds(16B)/thread
  auto stage_half = [&](uint32_t gRowByte, uint32_t ldsHalfBase, int ktAbs) {
    const uint32_t g0 = gRowByte + (uint32_t)ktAbs * 128u;
#pragma unroll
    for (int q = 0; q < 2; q++) {
      __builtin_amdgcn_global_load_lds(
          (const AS1 void*)(zbC + (g0 + (uint32_t)q * (64u * KDIM * 2u) + vOff)),
          (AS3 void*)(smem + (ldsHalfBase + (uint32_t)q * 8192u + Pt)), 16, 0, 0);
    }
  };

  // A ds-read address regs: buf toggled by ^32768, kk by dedicated reg
  uint32_t vA0 = laneSwz + (uint32_t)wr * 16384u;
  uint32_t vA1 = vA0 ^ 64u;

  auto rdA = [&](int mi, int kk) -> s16x8 {
    return *(const s16x8*)(smem + ((kk ? vA1 : vA0) + (uint32_t)(mi * 2048)));
  };

  f32x4 acc[8][4];
#pragma unroll
  for (int m = 0; m < 8; m++)
#pragma unroll
    for (int n = 0; n < 4; n++) acc[m][n] = (f32x4){0.f, 0.f, 0.f, 0.f};

  s16x8 bbE[4][2], bbO[4][2];

  // prologue: A(kts)->buf0; B(kts)->bbE; B(kts+1)->bbO
  stage_half(gA0, 0u,      kts);
  stage_half(gA1, 16384u,  kts);
  asm volatile("" ::: "memory");   // pin: B loads below may not hoist above staging
#pragma unroll
  for (int n = 0; n < 4; n++) {
    bbE[n][0] = *(const s16x8*)(zbC + bOff[n]);
    bbE[n][1] = *(const s16x8*)(zbC + bOff[n] + 64u);
  }
  asm volatile("" ::: "memory");
#pragma unroll
  for (int n = 0; n < 4; n++) {
    bbO[n][0] = *(const s16x8*)(zbC + bOff[n] + 128u);
    bbO[n][1] = *(const s16x8*)(zbC + bOff[n] + 192u);
  }
  asm volatile("" ::: "memory");
#pragma unroll
  for (int n = 0; n < 4; n++) bOff[n] += 256u;   // -> points at K-tile kts+2
  asm volatile("s_waitcnt vmcnt(8)" ::: "memory");  // A(kts)+bbE landed; bbO in flight
  __builtin_amdgcn_s_barrier();

  // one K-tile: 4 phases, each {read 2 A-frag pairs [, stage A-half]; barrier;
  // 16 MFMA; barrier}; end: reload bcur with B(T+2), counted vmcnt.
  auto ktile = [&](s16x8 (&bcur)[4][2], int T) {
    const bool stA = (T + 1 < cnt);
    const bool ldB = (T + 2 < cnt);
    const uint32_t so = (uint32_t)((T + 1) & 1) * 32768u;  // idle A buffer
    const int ktA = kts + T + 1;

    // p0: a0,a1 ; stage A0(T+1)
    {
      s16x8 ax[2][2];
#pragma unroll
      for (int m = 0; m < 2; m++) { ax[m][0] = rdA(m, 0); ax[m][1] = rdA(m, 1); }
      if (stA) stage_half(gA0, so, ktA);
      __builtin_amdgcn_s_barrier();
      __builtin_amdgcn_s_setprio(1);
#pragma unroll
      for (int m = 0; m < 2; m++)
#pragma unroll
        for (int n = 0; n < 4; n++) {
          acc[m][n] = __builtin_amdgcn_mfma_f32_16x16x32_bf16(ax[m][0], bcur[n][0], acc[m][n], 0, 0, 0);
          acc[m][n] = __builtin_amdgcn_mfma_f32_16x16x32_bf16(ax[m][1], bcur[n][1], acc[m][n], 0, 0, 0);
        }
      __builtin_amdgcn_s_setprio(0);
      __builtin_amdgcn_s_barrier();
    }
    // p1: a2,a3 ; stage A1(T+1)
    {
      s16x8 ax[2][2];
#pragma unroll
      for (int m = 0; m < 2; m++) { ax[m][0] = rdA(m + 2, 0); ax[m][1] = rdA(m + 2, 1); }
      if (stA) stage_half(gA1, so + 16384u, ktA);
      __builtin_amdgcn_s_barrier();
      __builtin_amdgcn_s_setprio(1);
#pragma unroll
      for (int m = 0; m < 2; m++)
#pragma unroll
        for (int n = 0; n < 4; n++) {
          acc[m + 2][n] = __builtin_amdgcn_mfma_f32_16x16x32_bf16(ax[m][0], bcur[n][0], acc[m + 2][n], 0, 0, 0);
          acc[m + 2][n] = __builtin_amdgcn_mfma_f32_16x16x32_bf16(ax[m][1], bcur[n][1], acc[m + 2][n], 0, 0, 0);
        }
      __builtin_amdgcn_s_setprio(0);
      __builtin_amdgcn_s_barrier();
    }
    // p2: a4,a5
    {
      s16x8 ax[2][2];
#pragma unroll
      for (int m = 0; m < 2; m++) { ax[m][0] = rdA(m + 4, 0); ax[m][1] = rdA(m + 4, 1); }
      __builtin_amdgcn_s_barrier();
      __builtin_amdgcn_s_setprio(1);
#pragma unroll
      for (int m = 0; m < 2; m++)
#pragma unroll
        for (int n = 0; n < 4; n++) {
          acc[m + 4][n] = __builtin_amdgcn_mfma_f32_16x16x32_bf16(ax[m][0], bcur[n][0], acc[m + 4][n], 0, 0, 0);
          acc[m + 4][n] = __builtin_amdgcn_mfma_f32_16x16x32_bf16(ax[m][1], bcur[n][1], acc[m + 4][n], 0, 0, 0);
        }
      __builtin_amdgcn_s_setprio(0);
      __builtin_amdgcn_s_barrier();
    }
    // p3: a6,a7 ; then reload bcur with B(T+2); counted vmcnt
    {
      s16x8 ax[2][2];
#pragma unroll
      for (int m = 0; m < 2; m++) { ax[m][0] = rdA(m + 6, 0); ax[m][1] = rdA(m + 6, 1); }
      __builtin_amdgcn_s_barrier();
      __builtin_amdgcn_s_setprio(1);
#pragma unroll
      for (int m = 0; m < 2; m++)
#pragma unroll
        for (int n = 0; n < 4; n++) {
          acc[m + 6][n] = __builtin_amdgcn_mfma_f32_16x16x32_bf16(ax[m][0], bcur[n][0], acc[m + 6][n], 0, 0, 0);
          acc[m + 6][n] = __builtin_amdgcn_mfma_f32_16x16x32_bf16(ax[m][1], bcur[n][1], acc[m + 6][n], 0, 0, 0);
        }
      __builtin_amdgcn_s_setprio(0);
      asm volatile("" ::: "memory");   // pin: B issue stays after A staging above
      if (ldB) {
#pragma unroll
        for (int n = 0; n < 4; n++) {
          bcur[n][0] = *(const s16x8*)(zbC + bOff[n]);
          bcur[n][1] = *(const s16x8*)(zbC + bOff[n] + 64u);
        }
      }
#pragma unroll
      for (int n = 0; n < 4; n++) bOff[n] += 128u;
      asm volatile("" ::: "memory");
      // vmcnt(8): drains B(T+1) + A(T+1) stages; leaves B(T+2) (8) in flight
      if (ldB) { asm volatile("s_waitcnt vmcnt(8)" ::: "memory"); }
      else     { asm volatile("s_waitcnt vmcnt(0)" ::: "memory"); }
      __builtin_amdgcn_s_barrier();
      vA0 ^= 32768u; vA1 ^= 32768u;
    }
  };

  int T = 0;
  for (; T + 1 < cnt; T += 2) {
    ktile(bbE, T);
    ktile(bbO, T + 1);
  }
  if (T < cnt) ktile(bbE, T);   // cnt odd: tail tile (parity even -> bbE)

  // epilogue: tile-local 256x256 partial, non-atomic full write
  // C/D layout (m89): col = lane&15, row = (lane>>4)*4 + reg
  float* outp = pbuf + (size_t)pidx * 65536;
  const int r0 = wr * 128 + ((lane >> 4) << 2);
  const int c0 = wc * 64 + (lane & 15);
#pragma unroll
  for (int m = 0; m < 8; m++)
#pragma unroll
    for (int n = 0; n < 4; n++)
#pragma unroll
      for (int rg = 0; rg < 4; rg++)
        outp[(size_t)(r0 + m * 16 + rg) * 256 + (c0 + n * 16)] = acc[m][n][rg];
}

// helpers: tile id from (ti<=tj)
__device__ __forceinline__ int tile_id(int ti, int tj) {
  return 4 * ti - ((ti * (ti - 1)) >> 1) + (tj - ti);
}

// ---- diag_n[i] = g[i][i] * inv_i^2 ----
__global__ void k_diag(const float* __restrict__ pbuf, const float* __restrict__ inv_norm,
                       float* __restrict__ diag) {
  const int i = blockIdx.x * 256 + threadIdx.x;
  const int ti = i >> 8;
  const int t = tile_id(ti, ti);
  const int off = (i & 255) * 257;
  float s = 0.f;
  for (int c = 0; c < NCHUNK; ++c)
    s += pbuf[(size_t)(t * NCHUNK + c) * 65536 + off];
  const float w = inv_norm[i];
  diag[i] = s * w * w;
}

// ---- accum = sum_{i<j} exp(-max(d_i + d_j - 2 g_ij inv_i inv_j, 0)) ----
__global__ void k_expsum(const float* __restrict__ pbuf, const float* __restrict__ inv_norm,
                         const float* __restrict__ diag, float* __restrict__ accum) {
  const int gid = blockIdx.x * 256 + threadIdx.x;
  const int e0 = gid * 4;
  const int i  = e0 >> 10;
  const int j0 = e0 & 1023;
  const int ti = i >> 8, tj = j0 >> 8;
  float s = 0.f;
  if (tj >= ti && j0 + 3 > i) {
    const int t = tile_id(ti, tj);
    const int off = (i & 255) * 256 + (j0 & 255);
    float gx = 0.f, gy = 0.f, gz = 0.f, gw = 0.f;
    for (int c = 0; c < NCHUNK; ++c) {
      const float4 v = *(const float4*)(pbuf + (size_t)(t * NCHUNK + c) * 65536 + off);
      gx += v.x; gy += v.y; gz += v.z; gw += v.w;
    }
    const float wi = inv_norm[i];
    const float di = diag[i];
    const float4 wj = *(const float4*)(inv_norm + j0);
    const float4 dj = *(const float4*)(diag + j0);
    float gn, d2;
    gn = gx * wi * wj.x; d2 = fmaxf(di + dj.x - 2.f * gn, 0.f); if (i < j0 + 0) s += expf(-d2);
    gn = gy * wi * wj.y; d2 = fmaxf(di + dj.y - 2.f * gn, 0.f); if (i < j0 + 1) s += expf(-d2);
    gn = gz * wi * wj.z; d2 = fmaxf(di + dj.z - 2.f * gn, 0.f); if (i < j0 + 2) s += expf(-d2);
    gn = gw * wi * wj.w; d2 = fmaxf(di + dj.w - 2.f * gn, 0.f); if (i < j0 + 3) s += expf(-d2);
  }
  for (int off = 32; off; off >>= 1) s += __shfl_down(s, off, 64);
  __shared__ float part[4];
  const int lane = threadIdx.x & 63, w = threadIdx.x >> 6;
  if (lane == 0) part[w] = s;
  __syncthreads();
  if (threadIdx.x == 0) atomicAdd(accum, part[0] + part[1] + part[2] + part[3]);
}

__global__ void k_final(const float* __restrict__ accum, float* __restrict__ out) {
  const float n_pairs = (float)NROWS * (float)(NROWS - 1) * 0.5f;
  out[0] = 0.25f * logf(accum[0] / n_pairs);
}

extern "C" void kernel_launch(void* const* d_in, const int* in_sizes, int n_in,
                              void* d_out, int out_size, void* d_ws, size_t ws_size,
                              hipStream_t stream) {
  const float* z = (const float*)d_in[0];
  float* out = (float*)d_out;
  char* ws = (char*)d_ws;

  // layout: inv_norm 4KB | diag 4KB | accum | ... | pbuf 62.5MB | zb 128MB
  float*  inv_norm = (float*)(ws);
  float*  diag     = (float*)(ws + 4096);
  float*  accum    = (float*)(ws + 8192);
  float*  pbuf     = (float*)(ws + 65536);
  ushort* zbuf     = (ushort*)(ws + 65536 + (size_t)PARTN * 65536 * sizeof(float));

  hipMemsetAsync(accum, 0, sizeof(float), stream);

  k_prep<<<NROWS, 256, 0, stream>>>(z, zbuf, inv_norm);

  hipFuncSetAttribute(reinterpret_cast<const void*>(&k_gram8),
                      hipFuncAttributeMaxDynamicSharedMemorySize, 65536);
  k_gram8<<<PARTN, 512, 65536, stream>>>(zbuf, pbuf);

  k_diag<<<NROWS / 256, 256, 0, stream>>>(pbuf, inv_norm, diag);
  k_expsum<<<(NROWS * NROWS / 4) / 256, 256, 0, stream>>>(pbuf, inv_norm, diag, accum);
  k_final<<<1, 1, 0, stream>>>(accum, out);
}

// Round 10
// 200.078 us; speedup vs baseline: 1.2774x; 1.2774x over previous
//
#include <hip/hip_runtime.h>
#include <hip/hip_bf16.h>
#include <stdint.h>

// DispersiveLoss: B=1024 rows, D=65536.
// R10: revert R9 (B back in LDS; R8 structure) + m201 prefetch depth:
// 3 half-tiles in flight across barriers (vmcnt(6)), stage schedule
// A1(T+1)@p0 / B0(T+2)@p2 / B1(T+2)+A0(T+2)@p3 (race-free: each region's
// last ds_read is >=1 barrier before its overwrite), quadrant MFMA order
// (p3 = pure MFMA). Decomposition: 250 blocks = 10 upper-tri 256^2 tiles
// x 25 K-chunks, XCD-grouped for L2 sharing; 3-bit XOR swizzle; reg-lean
// addressing (R7).

#define NROWS 1024
#define KDIM  65536
#define BK    64
#define NCHUNK 25         // K-chunks per tile
#define CHUNK0 41         // K-tiles per chunk (last chunk: 40)
#define PARTN  250        // 10 tiles * 25 chunks

typedef __attribute__((ext_vector_type(8))) short  s16x8;
typedef __attribute__((ext_vector_type(4))) float  f32x4;

#define AS1 __attribute__((address_space(1)))
#define AS3 __attribute__((address_space(3)))

__device__ __forceinline__ ushort f2bf(float f) {
  uint32_t u = __float_as_uint(f);
  return (ushort)((u + 0x7fffu + ((u >> 16) & 1u)) >> 16);  // RNE bf16
}

// ---- fused: row sum-of-squares -> inv_norm, plus raw fp32 -> bf16 cast ----
__global__ void k_prep(const float* __restrict__ z, ushort* __restrict__ zb,
                       float* __restrict__ inv_norm) {
  const int row = blockIdx.x;
  const float4* zr = (const float4*)(z + (size_t)row * KDIM);
  ushort* br = zb + (size_t)row * KDIM;
  float ss = 0.f;
  for (int i = threadIdx.x; i < KDIM / 4; i += blockDim.x) {
    const float4 v = zr[i];
    ss += v.x * v.x + v.y * v.y + v.z * v.z + v.w * v.w;
    ushort4 o;
    o.x = f2bf(v.x); o.y = f2bf(v.y); o.z = f2bf(v.z); o.w = f2bf(v.w);
    ((ushort4*)br)[i] = o;
  }
  for (int off = 32; off; off >>= 1) ss += __shfl_down(ss, off, 64);
  __shared__ float part[4];
  const int lane = threadIdx.x & 63, w = threadIdx.x >> 6;
  if (lane == 0) part[w] = ss;
  __syncthreads();
  if (threadIdx.x == 0) {
    const float t = part[0] + part[1] + part[2] + part[3];
    inv_norm[row] = 1.f / fmaxf(sqrtf(t), 1e-12f);
  }
}

// ---- 256^2 Gram: A+B in LDS (128KB dbuf), depth-3 counted-vmcnt pipeline ----
__global__
__attribute__((amdgpu_flat_work_group_size(512, 512), amdgpu_waves_per_eu(2, 2)))
void k_gram8(const ushort* __restrict__ zb, float* __restrict__ pbuf) {
  extern __shared__ char smem[];
  const int tid  = threadIdx.x;
  const int lane = tid & 63;
  const int wid  = tid >> 6;
  const int wr   = wid >> 2;     // 0..1  (M half)
  const int wc   = wid & 3;      // 0..3  (N quarter)

  // bijective XCD swizzle inverse (n=250, q=31, r=2)
  const int d   = blockIdx.x;
  const int xcd = d & 7, idx = d >> 3;
  const int l   = (xcd < 2) ? xcd * 32 + idx : 64 + (xcd - 2) * 31 + idx;
  const int kc   = l / 10;        // 0..24
  const int tile = l - kc * 10;   // 0..9
  const int kts  = kc * CHUNK0;
  const int cnt  = (kc == NCHUNK - 1) ? 40 : CHUNK0;
  const int pidx = tile * NCHUNK + kc;

  const int tm = (tile < 4) ? 0 : (tile < 7) ? 1 : (tile < 9) ? 2 : 3;
  const int tbase = 4 * tm - ((tm * (tm - 1)) >> 1);
  const int tn = tile - tbase + tm;

  // staging per-thread constant (pre-swizzled source; linear LDS dest)
  const uint32_t Pt   = (uint32_t)tid * 16u;
  const uint32_t Lt   = Pt ^ (((Pt >> 7) & 7u) << 4);
  const uint32_t vOff = (Lt >> 7) * (uint32_t)(KDIM * 2) + (Lt & 127u);

  // ds-read per-thread constant: swizzled lane base ((L>>7)&7 == lane&7)
  const uint32_t laneRB  = (uint32_t)(lane & 15) * 128u + (uint32_t)(lane >> 4) * 16u;
  const uint32_t laneSwz = laneRB ^ (((uint32_t)lane & 7u) << 4);

  const char* zbC = (const char*)zb;

  // panel row-byte bases (halves)
  const uint32_t gA0 = (uint32_t)(tm * 256) * (uint32_t)(KDIM * 2);
  const uint32_t gA1 = gA0 + 128u * (uint32_t)(KDIM * 2);
  const uint32_t gB0 = (uint32_t)(tn * 256) * (uint32_t)(KDIM * 2);
  const uint32_t gB1 = gB0 + 128u * (uint32_t)(KDIM * 2);

  // stage one 128x64 half-tile (16 KB): 2 x global_load_lds(16B)/thread
  auto stage_half = [&](uint32_t gRowByte, uint32_t ldsHalfBase, int ktAbs) {
    const uint32_t g0 = gRowByte + (uint32_t)ktAbs * 128u;
#pragma unroll
    for (int q = 0; q < 2; q++) {
      __builtin_amdgcn_global_load_lds(
          (const AS1 void*)(zbC + (g0 + (uint32_t)q * (64u * KDIM * 2u) + vOff)),
          (AS3 void*)(smem + (ldsHalfBase + (uint32_t)q * 8192u + Pt)), 16, 0, 0);
    }
  };

  // ds-read address regs: buf toggled by ^32768, kk via dedicated reg
  uint32_t vA0 = laneSwz + (uint32_t)wr * 16384u;
  uint32_t vA1 = vA0 ^ 64u;
  uint32_t vB0 = laneSwz + 65536u + (uint32_t)(wc >> 1) * 16384u
               + (uint32_t)(wc & 1) * 8192u;
  uint32_t vB1 = vB0 ^ 64u;

  auto rdA = [&](int mi, int kk) -> s16x8 {
    return *(const s16x8*)(smem + ((kk ? vA1 : vA0) + (uint32_t)(mi * 2048)));
  };
  auto rdB = [&](int ni, int kk) -> s16x8 {
    return *(const s16x8*)(smem + ((kk ? vB1 : vB0) + (uint32_t)(ni * 2048)));
  };

  f32x4 acc[8][4];
#pragma unroll
  for (int m = 0; m < 8; m++)
#pragma unroll
    for (int n = 0; n < 4; n++) acc[m][n] = (f32x4){0.f, 0.f, 0.f, 0.f};

  // prologue: all 4 halves of K-tile kts -> buf0; B0,B1,A0 of kts+1 -> buf1
  // (A1(kts+1) staged at T=0.p0). Leaves 3 half-tiles in flight after drain.
  stage_half(gB0, 65536u,           kts);
  stage_half(gB1, 65536u + 16384u,  kts);
  stage_half(gA0, 0u,               kts);
  stage_half(gA1, 16384u,           kts);
  stage_half(gB0, 65536u + 32768u,           kts + 1);
  stage_half(gB1, 65536u + 32768u + 16384u,  kts + 1);
  stage_half(gA0, 32768u,                    kts + 1);
  asm volatile("s_waitcnt vmcnt(6)" ::: "memory");  // K-tile kts fully landed
  __builtin_amdgcn_s_barrier();

  s16x8 aF[4][2], bb[4][2];
  for (int T = 0; T < cnt; ++T) {
    const uint32_t cur  = (uint32_t)(T & 1) * 32768u;        // buf being read
    const uint32_t idle = cur ^ 32768u;                      // buf of T+1
    const bool stA = (T + 1 < cnt);
    const bool stB = (T + 2 < cnt);
    const int ktA = kts + T + 1;
    const int ktB = kts + T + 2;

    // ---- p0: read a0-3 + b0-1 ; stage A1(T+1) [idle A1: last read T-1.p2] ----
    {
#pragma unroll
      for (int m = 0; m < 4; m++) { aF[m][0] = rdA(m, 0); aF[m][1] = rdA(m, 1); }
#pragma unroll
      for (int n = 0; n < 2; n++) { bb[n][0] = rdB(n, 0); bb[n][1] = rdB(n, 1); }
      if (stA) stage_half(gA1, idle + 16384u, ktA);
      __builtin_amdgcn_s_barrier();
      __builtin_amdgcn_s_setprio(1);
#pragma unroll
      for (int m = 0; m < 4; m++)
#pragma unroll
        for (int n = 0; n < 2; n++) {
          acc[m][n] = __builtin_amdgcn_mfma_f32_16x16x32_bf16(aF[m][0], bb[n][0], acc[m][n], 0, 0, 0);
          acc[m][n] = __builtin_amdgcn_mfma_f32_16x16x32_bf16(aF[m][1], bb[n][1], acc[m][n], 0, 0, 0);
        }
      __builtin_amdgcn_s_setprio(0);
      __builtin_amdgcn_s_barrier();
    }

    // ---- p1: read b2-3 ; no stage ; MFMA [0-3]x[2-3] ----
    {
#pragma unroll
      for (int n = 2; n < 4; n++) { bb[n][0] = rdB(n, 0); bb[n][1] = rdB(n, 1); }
      __builtin_amdgcn_s_barrier();
      __builtin_amdgcn_s_setprio(1);
#pragma unroll
      for (int m = 0; m < 4; m++)
#pragma unroll
        for (int n = 2; n < 4; n++) {
          acc[m][n] = __builtin_amdgcn_mfma_f32_16x16x32_bf16(aF[m][0], bb[n][0], acc[m][n], 0, 0, 0);
          acc[m][n] = __builtin_amdgcn_mfma_f32_16x16x32_bf16(aF[m][1], bb[n][1], acc[m][n], 0, 0, 0);
        }
      __builtin_amdgcn_s_setprio(0);
      __builtin_amdgcn_s_barrier();
    }

    // ---- p2: read a4-7 (overwrite aF) ; stage B0(T+2) [cur B0: reads done p1] ;
    //          MFMA [4-7]x[0-1] ----
    {
#pragma unroll
      for (int m = 0; m < 4; m++) { aF[m][0] = rdA(m + 4, 0); aF[m][1] = rdA(m + 4, 1); }
      if (stB) stage_half(gB0, 65536u + cur, ktB);
      __builtin_amdgcn_s_barrier();
      __builtin_amdgcn_s_setprio(1);
#pragma unroll
      for (int m = 0; m < 4; m++)
#pragma unroll
        for (int n = 0; n < 2; n++) {
          acc[m + 4][n] = __builtin_amdgcn_mfma_f32_16x16x32_bf16(aF[m][0], bb[n][0], acc[m + 4][n], 0, 0, 0);
          acc[m + 4][n] = __builtin_amdgcn_mfma_f32_16x16x32_bf16(aF[m][1], bb[n][1], acc[m + 4][n], 0, 0, 0);
        }
      __builtin_amdgcn_s_setprio(0);
      __builtin_amdgcn_s_barrier();
    }

    // ---- p3: stage B1(T+2) + A0(T+2) [cur regions: reads done p1/p2] ;
    //          pure MFMA [4-7]x[2-3] ; counted vmcnt(6) ----
    {
      if (stB) {
        stage_half(gB1, 65536u + cur + 16384u, ktB);
        stage_half(gA0, cur,                   ktB);
      }
      __builtin_amdgcn_s_barrier();
      __builtin_amdgcn_s_setprio(1);
#pragma unroll
      for (int m = 0; m < 4; m++)
#pragma unroll
        for (int n = 2; n < 4; n++) {
          acc[m + 4][n] = __builtin_amdgcn_mfma_f32_16x16x32_bf16(aF[m][0], bb[n][0], acc[m + 4][n], 0, 0, 0);
          acc[m + 4][n] = __builtin_amdgcn_mfma_f32_16x16x32_bf16(aF[m][1], bb[n][1], acc[m + 4][n], 0, 0, 0);
        }
      __builtin_amdgcn_s_setprio(0);
      // vmcnt(6): drains all of T+1's halves (B0,B1,A0 from T-1/T prologue path
      // + A1 from this tile's p0); leaves B0,B1,A0 of T+2 (6 loads) in flight.
      if (stB) { asm volatile("s_waitcnt vmcnt(6)" ::: "memory"); }
      else     { asm volatile("s_waitcnt vmcnt(0)" ::: "memory"); }
      __builtin_amdgcn_s_barrier();
      vA0 ^= 32768u; vA1 ^= 32768u; vB0 ^= 32768u; vB1 ^= 32768u;
    }
  }

  // epilogue: tile-local 256x256 partial, non-atomic full write
  // C/D layout (m89): col = lane&15, row = (lane>>4)*4 + reg
  float* outp = pbuf + (size_t)pidx * 65536;
  const int r0 = wr * 128 + ((lane >> 4) << 2);
  const int c0 = wc * 64 + (lane & 15);
#pragma unroll
  for (int m = 0; m < 8; m++)
#pragma unroll
    for (int n = 0; n < 4; n++)
#pragma unroll
      for (int rg = 0; rg < 4; rg++)
        outp[(size_t)(r0 + m * 16 + rg) * 256 + (c0 + n * 16)] = acc[m][n][rg];
}

// helpers: tile id from (ti<=tj)
__device__ __forceinline__ int tile_id(int ti, int tj) {
  return 4 * ti - ((ti * (ti - 1)) >> 1) + (tj - ti);
}

// ---- diag_n[i] = g[i][i] * inv_i^2 ----
__global__ void k_diag(const float* __restrict__ pbuf, const float* __restrict__ inv_norm,
                       float* __restrict__ diag) {
  const int i = blockIdx.x * 256 + threadIdx.x;
  const int ti = i >> 8;
  const int t = tile_id(ti, ti);
  const int off = (i & 255) * 257;
  float s = 0.f;
  for (int c = 0; c < NCHUNK; ++c)
    s += pbuf[(size_t)(t * NCHUNK + c) * 65536 + off];
  const float w = inv_norm[i];
  diag[i] = s * w * w;
}

// ---- accum = sum_{i<j} exp(-max(d_i + d_j - 2 g_ij inv_i inv_j, 0)) ----
__global__ void k_expsum(const float* __restrict__ pbuf, const float* __restrict__ inv_norm,
                         const float* __restrict__ diag, float* __restrict__ accum) {
  const int gid = blockIdx.x * 256 + threadIdx.x;
  const int e0 = gid * 4;
  const int i  = e0 >> 10;
  const int j0 = e0 & 1023;
  const int ti = i >> 8, tj = j0 >> 8;
  float s = 0.f;
  if (tj >= ti && j0 + 3 > i) {
    const int t = tile_id(ti, tj);
    const int off = (i & 255) * 256 + (j0 & 255);
    float gx = 0.f, gy = 0.f, gz = 0.f, gw = 0.f;
    for (int c = 0; c < NCHUNK; ++c) {
      const float4 v = *(const float4*)(pbuf + (size_t)(t * NCHUNK + c) * 65536 + off);
      gx += v.x; gy += v.y; gz += v.z; gw += v.w;
    }
    const float wi = inv_norm[i];
    const float di = diag[i];
    const float4 wj = *(const float4*)(inv_norm + j0);
    const float4 dj = *(const float4*)(diag + j0);
    float gn, d2;
    gn = gx * wi * wj.x; d2 = fmaxf(di + dj.x - 2.f * gn, 0.f); if (i < j0 + 0) s += expf(-d2);
    gn = gy * wi * wj.y; d2 = fmaxf(di + dj.y - 2.f * gn, 0.f); if (i < j0 + 1) s += expf(-d2);
    gn = gz * wi * wj.z; d2 = fmaxf(di + dj.z - 2.f * gn, 0.f); if (i < j0 + 2) s += expf(-d2);
    gn = gw * wi * wj.w; d2 = fmaxf(di + dj.w - 2.f * gn, 0.f); if (i < j0 + 3) s += expf(-d2);
  }
  for (int off = 32; off; off >>= 1) s += __shfl_down(s, off, 64);
  __shared__ float part[4];
  const int lane = threadIdx.x & 63, w = threadIdx.x >> 6;
  if (lane == 0) part[w] = s;
  __syncthreads();
  if (threadIdx.x == 0) atomicAdd(accum, part[0] + part[1] + part[2] + part[3]);
}

__global__ void k_final(const float* __restrict__ accum, float* __restrict__ out) {
  const float n_pairs = (float)NROWS * (float)(NROWS - 1) * 0.5f;
  out[0] = 0.25f * logf(accum[0] / n_pairs);
}

extern "C" void kernel_launch(void* const* d_in, const int* in_sizes, int n_in,
                              void* d_out, int out_size, void* d_ws, size_t ws_size,
                              hipStream_t stream) {
  const float* z = (const float*)d_in[0];
  float* out = (float*)d_out;
  char* ws = (char*)d_ws;

  // layout: inv_norm 4KB | diag 4KB | accum | ... | pbuf 62.5MB | zb 128MB
  float*  inv_norm = (float*)(ws);
  float*  diag     = (float*)(ws + 4096);
  float*  accum    = (float*)(ws + 8192);
  float*  pbuf     = (float*)(ws + 65536);
  ushort* zbuf     = (ushort*)(ws + 65536 + (size_t)PARTN * 65536 * sizeof(float));

  hipMemsetAsync(accum, 0, sizeof(float), stream);

  k_prep<<<NROWS, 256, 0, stream>>>(z, zbuf, inv_norm);

  hipFuncSetAttribute(reinterpret_cast<const void*>(&k_gram8),
                      hipFuncAttributeMaxDynamicSharedMemorySize, 131072);
  k_gram8<<<PARTN, 512, 131072, stream>>>(zbuf, pbuf);

  k_diag<<<NROWS / 256, 256, 0, stream>>>(pbuf, inv_norm, diag);
  k_expsum<<<(NROWS * NROWS / 4) / 256, 256, 0, stream>>>(pbuf, inv_norm, diag, accum);
  k_final<<<1, 1, 0, stream>>>(accum, out);
}

// Round 11
// 186.641 us; speedup vs baseline: 1.3694x; 1.0720x over previous
//
#include <hip/hip_runtime.h>
#include <hip/hip_bf16.h>
#include <stdint.h>

// DispersiveLoss: B=1024 rows, D=65536.
// R11: fp8-e4m3 Gram. R10 analysis: staging demand 6.4 TB/s from an
// L2-overflowing working set + LDS co-saturation = bandwidth wall; fp8
// halves staged bytes AND LDS bytes at unchanged MFMA rate. BK=128 fp8
// keeps the half-tile geometry byte-identical to R10 (128 rows x 128 B,
// 16 KB halves, same XOR-involution swizzle, same stage_half, same
// 4-phase vmcnt(6) schedule, same 250-block XCD-grouped decomposition).
// Conflict-free b64 frag reads via 8 precomputed swizzled addr regs
// (kk*32 overlaps swizzle bits -> exact XOR per (lane,kk), no folding).

#define NROWS 1024
#define KDIM  65536           // elements per row (= fp8 bytes per row)
#define NCHUNK 25             // K-chunks per tile
#define PARTN  250            // 10 tiles * 25 chunks

typedef __attribute__((ext_vector_type(4))) float f32x4;

#define AS1 __attribute__((address_space(1)))
#define AS3 __attribute__((address_space(3)))

// ---- fused: row sum-of-squares -> inv_norm, plus fp32 -> fp8 e4m3 cast ----
__global__ void k_prep(const float* __restrict__ z, uint32_t* __restrict__ zq,
                       float* __restrict__ inv_norm) {
  const int row = blockIdx.x;
  const float4* zr = (const float4*)(z + (size_t)row * KDIM);
  uint32_t* qr = zq + (size_t)row * (KDIM / 4);
  float ss = 0.f;
  for (int i = threadIdx.x; i < KDIM / 4; i += blockDim.x) {
    const float4 v = zr[i];
    ss += v.x * v.x + v.y * v.y + v.z * v.z + v.w * v.w;
    int p = __builtin_amdgcn_cvt_pk_fp8_f32(v.x, v.y, 0, false);   // bytes 0,1
    p     = __builtin_amdgcn_cvt_pk_fp8_f32(v.z, v.w, p, true);    // bytes 2,3
    qr[i] = (uint32_t)p;
  }
  for (int off = 32; off; off >>= 1) ss += __shfl_down(ss, off, 64);
  __shared__ float part[4];
  const int lane = threadIdx.x & 63, w = threadIdx.x >> 6;
  if (lane == 0) part[w] = ss;
  __syncthreads();
  if (threadIdx.x == 0) {
    const float t = part[0] + part[1] + part[2] + part[3];
    inv_norm[row] = 1.f / fmaxf(sqrtf(t), 1e-12f);
  }
}

// ---- 256^2 fp8 Gram: BK=128, A+B in LDS (128KB dbuf), depth-3 vmcnt(6) ----
__global__
__attribute__((amdgpu_flat_work_group_size(512, 512), amdgpu_waves_per_eu(2, 2)))
void k_gram8(const unsigned char* __restrict__ zb, float* __restrict__ pbuf) {
  extern __shared__ char smem[];
  const int tid  = threadIdx.x;
  const int lane = tid & 63;
  const int wid  = tid >> 6;
  const int wr   = wid >> 2;     // 0..1  (M half)
  const int wc   = wid & 3;      // 0..3  (N quarter)

  // bijective XCD swizzle inverse (n=250, q=31, r=2)
  const int d   = blockIdx.x;
  const int xcd = d & 7, idx = d >> 3;
  const int l   = (xcd < 2) ? xcd * 32 + idx : 64 + (xcd - 2) * 31 + idx;
  const int kc   = l / 10;        // 0..24
  const int tile = l - kc * 10;   // 0..9
  // 512 K-tiles(128) per tile column: first 12 chunks take 21, rest 20
  const int kts  = (kc < 12) ? kc * 21 : 20 * kc + 12;
  const int cnt  = (kc < 12) ? 21 : 20;
  const int pidx = tile * NCHUNK + kc;

  const int tm = (tile < 4) ? 0 : (tile < 7) ? 1 : (tile < 9) ? 2 : 3;
  const int tbase = 4 * tm - ((tm * (tm - 1)) >> 1);
  const int tn = tile - tbase + tm;

  // staging per-thread constant (pre-swizzled source; linear LDS dest)
  const uint32_t Pt   = (uint32_t)tid * 16u;
  const uint32_t Lt   = Pt ^ (((Pt >> 7) & 7u) << 4);
  const uint32_t vOff = (Lt >> 7) * (uint32_t)KDIM + (Lt & 127u);  // rows = 64KB

  // frag-read swizzled address regs: addr = row*128 + ((kk*32 + g*8) ^ mask)
  // row&7 == lane&7 for every frag row (mi*16, ni*16, (wc&1)*64 are 0 mod 8).
  const uint32_t mask = ((uint32_t)lane & 7u) << 4;
  const uint32_t rowB = (uint32_t)(lane & 15) * 128u;
  const uint32_t g8   = ((uint32_t)lane >> 4) * 8u;
  uint32_t vAd[4], vBd[4];
#pragma unroll
  for (int kk = 0; kk < 4; kk++) {
    const uint32_t sw = ((uint32_t)(kk * 32) + g8) ^ mask;
    vAd[kk] = (uint32_t)wr * 16384u + rowB + sw;
    vBd[kk] = 65536u + (uint32_t)(wc >> 1) * 16384u + (uint32_t)(wc & 1) * 8192u
            + rowB + sw;
  }

  const char* zbC = (const char*)zb;

  // panel row-byte bases (halves); rows are KDIM bytes (fp8)
  const uint32_t gA0 = (uint32_t)(tm * 256) * (uint32_t)KDIM;
  const uint32_t gA1 = gA0 + 128u * (uint32_t)KDIM;
  const uint32_t gB0 = (uint32_t)(tn * 256) * (uint32_t)KDIM;
  const uint32_t gB1 = gB0 + 128u * (uint32_t)KDIM;

  // stage one 128x128B half-tile (16 KB): 2 x global_load_lds(16B)/thread
  auto stage_half = [&](uint32_t gRowByte, uint32_t ldsHalfBase, int ktAbs) {
    const uint32_t g0 = gRowByte + (uint32_t)ktAbs * 128u;
#pragma unroll
    for (int q = 0; q < 2; q++) {
      __builtin_amdgcn_global_load_lds(
          (const AS1 void*)(zbC + (g0 + (uint32_t)q * (64u * (uint32_t)KDIM) + vOff)),
          (AS3 void*)(smem + (ldsHalfBase + (uint32_t)q * 8192u + Pt)), 16, 0, 0);
    }
  };

  auto rdA = [&](int mi, int kk) -> long {
    return *(const long*)(smem + (vAd[kk] + (uint32_t)(mi * 2048)));
  };
  auto rdB = [&](int ni, int kk) -> long {
    return *(const long*)(smem + (vBd[kk] + (uint32_t)(ni * 2048)));
  };

  f32x4 acc[8][4];
#pragma unroll
  for (int m = 0; m < 8; m++)
#pragma unroll
    for (int n = 0; n < 4; n++) acc[m][n] = (f32x4){0.f, 0.f, 0.f, 0.f};

  // prologue: 4 halves of K-tile kts -> buf0; B0,B1,A0 of kts+1 -> buf1
  stage_half(gB0, 65536u,           kts);
  stage_half(gB1, 65536u + 16384u,  kts);
  stage_half(gA0, 0u,               kts);
  stage_half(gA1, 16384u,           kts);
  stage_half(gB0, 65536u + 32768u,           kts + 1);
  stage_half(gB1, 65536u + 32768u + 16384u,  kts + 1);
  stage_half(gA0, 32768u,                    kts + 1);
  asm volatile("s_waitcnt vmcnt(6)" ::: "memory");  // K-tile kts fully landed
  __builtin_amdgcn_s_barrier();

  long aF[4][4], bLo[2][4], bHi[2][4];
  for (int T = 0; T < cnt; ++T) {
    const uint32_t cur  = (uint32_t)(T & 1) * 32768u;
    const uint32_t idle = cur ^ 32768u;
    const bool stA = (T + 1 < cnt);
    const bool stB = (T + 2 < cnt);
    const int ktA = kts + T + 1;
    const int ktB = kts + T + 2;

    // ---- p0: read a0-3 (16) + b0-1 (8) ; stage A1(T+1) ; MFMA [0-3]x[0-1] ----
    {
#pragma unroll
      for (int m = 0; m < 4; m++)
#pragma unroll
        for (int kk = 0; kk < 4; kk++) aF[m][kk] = rdA(m, kk);
#pragma unroll
      for (int n = 0; n < 2; n++)
#pragma unroll
        for (int kk = 0; kk < 4; kk++) bLo[n][kk] = rdB(n, kk);
      if (stA) stage_half(gA1, idle + 16384u, ktA);
      __builtin_amdgcn_s_barrier();
      __builtin_amdgcn_s_setprio(1);
#pragma unroll
      for (int m = 0; m < 4; m++)
#pragma unroll
        for (int n = 0; n < 2; n++)
#pragma unroll
          for (int kk = 0; kk < 4; kk++)
            acc[m][n] = __builtin_amdgcn_mfma_f32_16x16x32_fp8_fp8(aF[m][kk], bLo[n][kk], acc[m][n], 0, 0, 0);
      __builtin_amdgcn_s_setprio(0);
      __builtin_amdgcn_s_barrier();
    }

    // ---- p1: read b2-3 (8) ; MFMA [0-3]x[2-3] ----
    {
#pragma unroll
      for (int n = 0; n < 2; n++)
#pragma unroll
        for (int kk = 0; kk < 4; kk++) bHi[n][kk] = rdB(n + 2, kk);
      __builtin_amdgcn_s_barrier();
      __builtin_amdgcn_s_setprio(1);
#pragma unroll
      for (int m = 0; m < 4; m++)
#pragma unroll
        for (int n = 0; n < 2; n++)
#pragma unroll
          for (int kk = 0; kk < 4; kk++)
            acc[m][n + 2] = __builtin_amdgcn_mfma_f32_16x16x32_fp8_fp8(aF[m][kk], bHi[n][kk], acc[m][n + 2], 0, 0, 0);
      __builtin_amdgcn_s_setprio(0);
      __builtin_amdgcn_s_barrier();
    }

    // ---- p2: read a4-7 (16, reuse aF) ; stage B0(T+2) [B reads done p1] ;
    //          MFMA [4-7]x[0-1] ----
    {
#pragma unroll
      for (int m = 0; m < 4; m++)
#pragma unroll
        for (int kk = 0; kk < 4; kk++) aF[m][kk] = rdA(m + 4, kk);
      if (stB) stage_half(gB0, 65536u + cur, ktB);
      __builtin_amdgcn_s_barrier();
      __builtin_amdgcn_s_setprio(1);
#pragma unroll
      for (int m = 0; m < 4; m++)
#pragma unroll
        for (int n = 0; n < 2; n++)
#pragma unroll
          for (int kk = 0; kk < 4; kk++)
            acc[m + 4][n] = __builtin_amdgcn_mfma_f32_16x16x32_fp8_fp8(aF[m][kk], bLo[n][kk], acc[m + 4][n], 0, 0, 0);
      __builtin_amdgcn_s_setprio(0);
      __builtin_amdgcn_s_barrier();
    }

    // ---- p3: stage B1(T+2)+A0(T+2) [reads done p1/p2] ; pure MFMA [4-7]x[2-3] ;
    //          counted vmcnt(6) ----
    {
      if (stB) {
        stage_half(gB1, 65536u + cur + 16384u, ktB);
        stage_half(gA0, cur,                   ktB);
      }
      __builtin_amdgcn_s_barrier();
      __builtin_amdgcn_s_setprio(1);
#pragma unroll
      for (int m = 0; m < 4; m++)
#pragma unroll
        for (int n = 0; n < 2; n++)
#pragma unroll
          for (int kk = 0; kk < 4; kk++)
            acc[m + 4][n + 2] = __builtin_amdgcn_mfma_f32_16x16x32_fp8_fp8(aF[m][kk], bHi[n][kk], acc[m + 4][n + 2], 0, 0, 0);
      __builtin_amdgcn_s_setprio(0);
      // vmcnt(6): drains T+1's 4 halves (incl. A1 from p0); leaves the 6 loads
      // of T+2 (B0,B1,A0) in flight.
      if (stB) { asm volatile("s_waitcnt vmcnt(6)" ::: "memory"); }
      else     { asm volatile("s_waitcnt vmcnt(0)" ::: "memory"); }
      __builtin_amdgcn_s_barrier();
#pragma unroll
      for (int kk = 0; kk < 4; kk++) { vAd[kk] ^= 32768u; vBd[kk] ^= 32768u; }
    }
  }

  // epilogue: tile-local 256x256 partial, non-atomic full write
  // C/D layout (m89, dtype-independent): col = lane&15, row = (lane>>4)*4 + reg
  float* outp = pbuf + (size_t)pidx * 65536;
  const int r0 = wr * 128 + ((lane >> 4) << 2);
  const int c0 = wc * 64 + (lane & 15);
#pragma unroll
  for (int m = 0; m < 8; m++)
#pragma unroll
    for (int n = 0; n < 4; n++)
#pragma unroll
      for (int rg = 0; rg < 4; rg++)
        outp[(size_t)(r0 + m * 16 + rg) * 256 + (c0 + n * 16)] = acc[m][n][rg];
}

// helpers: tile id from (ti<=tj)
__device__ __forceinline__ int tile_id(int ti, int tj) {
  return 4 * ti - ((ti * (ti - 1)) >> 1) + (tj - ti);
}

// ---- diag_n[i] = g[i][i] * inv_i^2 ----
__global__ void k_diag(const float* __restrict__ pbuf, const float* __restrict__ inv_norm,
                       float* __restrict__ diag) {
  const int i = blockIdx.x * 256 + threadIdx.x;
  const int ti = i >> 8;
  const int t = tile_id(ti, ti);
  const int off = (i & 255) * 257;
  float s = 0.f;
  for (int c = 0; c < NCHUNK; ++c)
    s += pbuf[(size_t)(t * NCHUNK + c) * 65536 + off];
  const float w = inv_norm[i];
  diag[i] = s * w * w;
}

// ---- accum = sum_{i<j} exp(-max(d_i + d_j - 2 g_ij inv_i inv_j, 0)) ----
__global__ void k_expsum(const float* __restrict__ pbuf, const float* __restrict__ inv_norm,
                         const float* __restrict__ diag, float* __restrict__ accum) {
  const int gid = blockIdx.x * 256 + threadIdx.x;
  const int e0 = gid * 4;
  const int i  = e0 >> 10;
  const int j0 = e0 & 1023;
  const int ti = i >> 8, tj = j0 >> 8;
  float s = 0.f;
  if (tj >= ti && j0 + 3 > i) {
    const int t = tile_id(ti, tj);
    const int off = (i & 255) * 256 + (j0 & 255);
    float gx = 0.f, gy = 0.f, gz = 0.f, gw = 0.f;
    for (int c = 0; c < NCHUNK; ++c) {
      const float4 v = *(const float4*)(pbuf + (size_t)(t * NCHUNK + c) * 65536 + off);
      gx += v.x; gy += v.y; gz += v.z; gw += v.w;
    }
    const float wi = inv_norm[i];
    const float di = diag[i];
    const float4 wj = *(const float4*)(inv_norm + j0);
    const float4 dj = *(const float4*)(diag + j0);
    float gn, d2;
    gn = gx * wi * wj.x; d2 = fmaxf(di + dj.x - 2.f * gn, 0.f); if (i < j0 + 0) s += expf(-d2);
    gn = gy * wi * wj.y; d2 = fmaxf(di + dj.y - 2.f * gn, 0.f); if (i < j0 + 1) s += expf(-d2);
    gn = gz * wi * wj.z; d2 = fmaxf(di + dj.z - 2.f * gn, 0.f); if (i < j0 + 2) s += expf(-d2);
    gn = gw * wi * wj.w; d2 = fmaxf(di + dj.w - 2.f * gn, 0.f); if (i < j0 + 3) s += expf(-d2);
  }
  for (int off = 32; off; off >>= 1) s += __shfl_down(s, off, 64);
  __shared__ float part[4];
  const int lane = threadIdx.x & 63, w = threadIdx.x >> 6;
  if (lane == 0) part[w] = s;
  __syncthreads();
  if (threadIdx.x == 0) atomicAdd(accum, part[0] + part[1] + part[2] + part[3]);
}

__global__ void k_final(const float* __restrict__ accum, float* __restrict__ out) {
  const float n_pairs = (float)NROWS * (float)(NROWS - 1) * 0.5f;
  out[0] = 0.25f * logf(accum[0] / n_pairs);
}

extern "C" void kernel_launch(void* const* d_in, const int* in_sizes, int n_in,
                              void* d_out, int out_size, void* d_ws, size_t ws_size,
                              hipStream_t stream) {
  const float* z = (const float*)d_in[0];
  float* out = (float*)d_out;
  char* ws = (char*)d_ws;

  // layout: inv_norm 4KB | diag 4KB | accum | ... | pbuf 62.5MB | zb(fp8) 64MB
  float*    inv_norm = (float*)(ws);
  float*    diag     = (float*)(ws + 4096);
  float*    accum    = (float*)(ws + 8192);
  float*    pbuf     = (float*)(ws + 65536);
  uint32_t* zq       = (uint32_t*)(ws + 65536 + (size_t)PARTN * 65536 * sizeof(float));

  hipMemsetAsync(accum, 0, sizeof(float), stream);

  k_prep<<<NROWS, 256, 0, stream>>>(z, zq, inv_norm);

  hipFuncSetAttribute(reinterpret_cast<const void*>(&k_gram8),
                      hipFuncAttributeMaxDynamicSharedMemorySize, 131072);
  k_gram8<<<PARTN, 512, 131072, stream>>>((const unsigned char*)zq, pbuf);

  k_diag<<<NROWS / 256, 256, 0, stream>>>(pbuf, inv_norm, diag);
  k_expsum<<<(NROWS * NROWS / 4) / 256, 256, 0, stream>>>(pbuf, inv_norm, diag, accum);
  k_final<<<1, 1, 0, stream>>>(accum, out);
}

// Round 12
// 179.167 us; speedup vs baseline: 1.4265x; 1.0417x over previous
//
#include <hip/hip_runtime.h>
#include <hip/hip_bf16.h>
#include <stdint.h>

// DispersiveLoss: B=1024 rows, D=65536.
// R12: remove the read|barrier|MFMA wall. R8/R10/R11 all pinned gram at
// ~120us because ds_reads and MFMAs sat in separate barrier regions ->
// LDS and MFMA pipes alternated (util 35%). Merging them into one region
// per phase lets the compiler emit counted lgkmcnt interleaves (m97
// evidence) so LDS service overlaps MFMA. 3 barriers/K-tile:
//   P01 {stage A1(T+1); read all B + a0-3; MFMA 64} bar
//   P2  {stage B0(T+2); read a4-7;          MFMA 32} bar
//   P3  {stage B1+A0(T+2);                  MFMA 32; vmcnt(6)} bar
// Everything else = R11 (fp8 e4m3 BK=128, XOR swizzle, 250-block
// XCD-grouped symmetric decomposition, reg-lean addressing).

#define NROWS 1024
#define KDIM  65536           // elements per row (= fp8 bytes per row)
#define NCHUNK 25             // K-chunks per tile
#define PARTN  250            // 10 tiles * 25 chunks

typedef __attribute__((ext_vector_type(4))) float f32x4;

#define AS1 __attribute__((address_space(1)))
#define AS3 __attribute__((address_space(3)))

// ---- fused: row sum-of-squares -> inv_norm, plus fp32 -> fp8 e4m3 cast ----
__global__ void k_prep(const float* __restrict__ z, uint32_t* __restrict__ zq,
                       float* __restrict__ inv_norm) {
  const int row = blockIdx.x;
  const float4* zr = (const float4*)(z + (size_t)row * KDIM);
  uint32_t* qr = zq + (size_t)row * (KDIM / 4);
  float ss = 0.f;
  for (int i = threadIdx.x; i < KDIM / 4; i += blockDim.x) {
    const float4 v = zr[i];
    ss += v.x * v.x + v.y * v.y + v.z * v.z + v.w * v.w;
    int p = __builtin_amdgcn_cvt_pk_fp8_f32(v.x, v.y, 0, false);   // bytes 0,1
    p     = __builtin_amdgcn_cvt_pk_fp8_f32(v.z, v.w, p, true);    // bytes 2,3
    qr[i] = (uint32_t)p;
  }
  for (int off = 32; off; off >>= 1) ss += __shfl_down(ss, off, 64);
  __shared__ float part[4];
  const int lane = threadIdx.x & 63, w = threadIdx.x >> 6;
  if (lane == 0) part[w] = ss;
  __syncthreads();
  if (threadIdx.x == 0) {
    const float t = part[0] + part[1] + part[2] + part[3];
    inv_norm[row] = 1.f / fmaxf(sqrtf(t), 1e-12f);
  }
}

// ---- 256^2 fp8 Gram: BK=128, A+B in LDS (128KB dbuf), 3-barrier K-tile ----
__global__
__attribute__((amdgpu_flat_work_group_size(512, 512), amdgpu_waves_per_eu(2, 2)))
void k_gram8(const unsigned char* __restrict__ zb, float* __restrict__ pbuf) {
  extern __shared__ char smem[];
  const int tid  = threadIdx.x;
  const int lane = tid & 63;
  const int wid  = tid >> 6;
  const int wr   = wid >> 2;     // 0..1  (M half)
  const int wc   = wid & 3;      // 0..3  (N quarter)

  // bijective XCD swizzle inverse (n=250, q=31, r=2)
  const int d   = blockIdx.x;
  const int xcd = d & 7, idx = d >> 3;
  const int l   = (xcd < 2) ? xcd * 32 + idx : 64 + (xcd - 2) * 31 + idx;
  const int kc   = l / 10;        // 0..24
  const int tile = l - kc * 10;   // 0..9
  // 512 K-tiles(128B) per tile column: first 12 chunks take 21, rest 20
  const int kts  = (kc < 12) ? kc * 21 : 20 * kc + 12;
  const int cnt  = (kc < 12) ? 21 : 20;
  const int pidx = tile * NCHUNK + kc;

  const int tm = (tile < 4) ? 0 : (tile < 7) ? 1 : (tile < 9) ? 2 : 3;
  const int tbase = 4 * tm - ((tm * (tm - 1)) >> 1);
  const int tn = tile - tbase + tm;

  // staging per-thread constant (pre-swizzled source; linear LDS dest)
  const uint32_t Pt   = (uint32_t)tid * 16u;
  const uint32_t Lt   = Pt ^ (((Pt >> 7) & 7u) << 4);
  const uint32_t vOff = (Lt >> 7) * (uint32_t)KDIM + (Lt & 127u);

  // frag-read swizzled address regs: addr = row*128 + ((kk*32 + g*8) ^ mask)
  const uint32_t mask = ((uint32_t)lane & 7u) << 4;
  const uint32_t rowB = (uint32_t)(lane & 15) * 128u;
  const uint32_t g8   = ((uint32_t)lane >> 4) * 8u;
  uint32_t vAd[4], vBd[4];
#pragma unroll
  for (int kk = 0; kk < 4; kk++) {
    const uint32_t sw = ((uint32_t)(kk * 32) + g8) ^ mask;
    vAd[kk] = (uint32_t)wr * 16384u + rowB + sw;
    vBd[kk] = 65536u + (uint32_t)(wc >> 1) * 16384u + (uint32_t)(wc & 1) * 8192u
            + rowB + sw;
  }

  const char* zbC = (const char*)zb;

  // panel row-byte bases (halves); rows are KDIM bytes (fp8)
  const uint32_t gA0 = (uint32_t)(tm * 256) * (uint32_t)KDIM;
  const uint32_t gA1 = gA0 + 128u * (uint32_t)KDIM;
  const uint32_t gB0 = (uint32_t)(tn * 256) * (uint32_t)KDIM;
  const uint32_t gB1 = gB0 + 128u * (uint32_t)KDIM;

  // stage one 128x128B half-tile (16 KB): 2 x global_load_lds(16B)/thread
  auto stage_half = [&](uint32_t gRowByte, uint32_t ldsHalfBase, int ktAbs) {
    const uint32_t g0 = gRowByte + (uint32_t)ktAbs * 128u;
#pragma unroll
    for (int q = 0; q < 2; q++) {
      __builtin_amdgcn_global_load_lds(
          (const AS1 void*)(zbC + (g0 + (uint32_t)q * (64u * (uint32_t)KDIM) + vOff)),
          (AS3 void*)(smem + (ldsHalfBase + (uint32_t)q * 8192u + Pt)), 16, 0, 0);
    }
  };

  auto rdA = [&](int mi, int kk) -> long {
    return *(const long*)(smem + (vAd[kk] + (uint32_t)(mi * 2048)));
  };
  auto rdB = [&](int ni, int kk) -> long {
    return *(const long*)(smem + (vBd[kk] + (uint32_t)(ni * 2048)));
  };

  f32x4 acc[8][4];
#pragma unroll
  for (int m = 0; m < 8; m++)
#pragma unroll
    for (int n = 0; n < 4; n++) acc[m][n] = (f32x4){0.f, 0.f, 0.f, 0.f};

  // prologue: 4 halves of K-tile kts -> buf0; B0,B1,A0 of kts+1 -> buf1
  stage_half(gB0, 65536u,           kts);
  stage_half(gB1, 65536u + 16384u,  kts);
  stage_half(gA0, 0u,               kts);
  stage_half(gA1, 16384u,           kts);
  stage_half(gB0, 65536u + 32768u,           kts + 1);
  stage_half(gB1, 65536u + 32768u + 16384u,  kts + 1);
  stage_half(gA0, 32768u,                    kts + 1);
  asm volatile("s_waitcnt vmcnt(6)" ::: "memory");  // K-tile kts fully landed
  __builtin_amdgcn_s_barrier();

  long aF[4][4], bLo[2][4], bHi[2][4];
  for (int T = 0; T < cnt; ++T) {
    const uint32_t cur  = (uint32_t)(T & 1) * 32768u;
    const uint32_t idle = cur ^ 32768u;
    const bool stA = (T + 1 < cnt);
    const bool stB = (T + 2 < cnt);
    const int ktA = kts + T + 1;
    const int ktB = kts + T + 2;

    // ---- P01: stage A1(T+1->idle); read all B + a0-3; MFMA m0-3 x n0-3 ----
    // No barrier between reads and MFMA: compiler interleaves counted
    // lgkmcnt waits so LDS service overlaps the MFMA cluster.
    {
      if (stA) stage_half(gA1, idle + 16384u, ktA);
#pragma unroll
      for (int n = 0; n < 2; n++)
#pragma unroll
        for (int kk = 0; kk < 4; kk++) bLo[n][kk] = rdB(n, kk);
#pragma unroll
      for (int n = 0; n < 2; n++)
#pragma unroll
        for (int kk = 0; kk < 4; kk++) bHi[n][kk] = rdB(n + 2, kk);
#pragma unroll
      for (int m = 0; m < 4; m++)
#pragma unroll
        for (int kk = 0; kk < 4; kk++) aF[m][kk] = rdA(m, kk);
      __builtin_amdgcn_s_setprio(1);
#pragma unroll
      for (int m = 0; m < 4; m++) {
#pragma unroll
        for (int n = 0; n < 2; n++)
#pragma unroll
          for (int kk = 0; kk < 4; kk++)
            acc[m][n] = __builtin_amdgcn_mfma_f32_16x16x32_fp8_fp8(aF[m][kk], bLo[n][kk], acc[m][n], 0, 0, 0);
#pragma unroll
        for (int n = 0; n < 2; n++)
#pragma unroll
          for (int kk = 0; kk < 4; kk++)
            acc[m][n + 2] = __builtin_amdgcn_mfma_f32_16x16x32_fp8_fp8(aF[m][kk], bHi[n][kk], acc[m][n + 2], 0, 0, 0);
      }
      __builtin_amdgcn_s_setprio(0);
      __builtin_amdgcn_s_barrier();   // B fully read -> B0 may be overwritten
    }

    // ---- P2: stage B0(T+2->cur); read a4-7; MFMA m4-7 x n0-1 ----
    {
      if (stB) stage_half(gB0, 65536u + cur, ktB);
#pragma unroll
      for (int m = 0; m < 4; m++)
#pragma unroll
        for (int kk = 0; kk < 4; kk++) aF[m][kk] = rdA(m + 4, kk);
      __builtin_amdgcn_s_setprio(1);
#pragma unroll
      for (int m = 0; m < 4; m++)
#pragma unroll
        for (int n = 0; n < 2; n++)
#pragma unroll
          for (int kk = 0; kk < 4; kk++)
            acc[m + 4][n] = __builtin_amdgcn_mfma_f32_16x16x32_fp8_fp8(aF[m][kk], bLo[n][kk], acc[m + 4][n], 0, 0, 0);
      __builtin_amdgcn_s_setprio(0);
      __builtin_amdgcn_s_barrier();   // cur-A reads done -> A0/B1 overwritable
    }

    // ---- P3: stage B1+A0(T+2->cur); pure MFMA m4-7 x n2-3; vmcnt(6) ----
    {
      if (stB) {
        stage_half(gB1, 65536u + cur + 16384u, ktB);
        stage_half(gA0, cur,                   ktB);
      }
      __builtin_amdgcn_s_setprio(1);
#pragma unroll
      for (int m = 0; m < 4; m++)
#pragma unroll
        for (int n = 0; n < 2; n++)
#pragma unroll
          for (int kk = 0; kk < 4; kk++)
            acc[m + 4][n + 2] = __builtin_amdgcn_mfma_f32_16x16x32_fp8_fp8(aF[m][kk], bHi[n][kk], acc[m + 4][n + 2], 0, 0, 0);
      __builtin_amdgcn_s_setprio(0);
      // vmcnt(6): drains T+1's 4 halves (A1 from P01 + B0,B1,A0 from T-1);
      // leaves T+2's 6 loads (B0 from P2, B1+A0 from P3) in flight.
      if (stB)      { asm volatile("s_waitcnt vmcnt(6)" ::: "memory"); }
      else if (stA) { asm volatile("s_waitcnt vmcnt(0)" ::: "memory"); }
      else          { asm volatile("s_waitcnt vmcnt(0)" ::: "memory"); }
      __builtin_amdgcn_s_barrier();
#pragma unroll
      for (int kk = 0; kk < 4; kk++) { vAd[kk] ^= 32768u; vBd[kk] ^= 32768u; }
    }
  }

  // epilogue: tile-local 256x256 partial, non-atomic full write
  // C/D layout (m89, dtype-independent): col = lane&15, row = (lane>>4)*4 + reg
  float* outp = pbuf + (size_t)pidx * 65536;
  const int r0 = wr * 128 + ((lane >> 4) << 2);
  const int c0 = wc * 64 + (lane & 15);
#pragma unroll
  for (int m = 0; m < 8; m++)
#pragma unroll
    for (int n = 0; n < 4; n++)
#pragma unroll
      for (int rg = 0; rg < 4; rg++)
        outp[(size_t)(r0 + m * 16 + rg) * 256 + (c0 + n * 16)] = acc[m][n][rg];
}

// helpers: tile id from (ti<=tj)
__device__ __forceinline__ int tile_id(int ti, int tj) {
  return 4 * ti - ((ti * (ti - 1)) >> 1) + (tj - ti);
}

// ---- diag_n[i] = g[i][i] * inv_i^2 ----
__global__ void k_diag(const float* __restrict__ pbuf, const float* __restrict__ inv_norm,
                       float* __restrict__ diag) {
  const int i = blockIdx.x * 256 + threadIdx.x;
  const int ti = i >> 8;
  const int t = tile_id(ti, ti);
  const int off = (i & 255) * 257;
  float s = 0.f;
  for (int c = 0; c < NCHUNK; ++c)
    s += pbuf[(size_t)(t * NCHUNK + c) * 65536 + off];
  const float w = inv_norm[i];
  diag[i] = s * w * w;
}

// ---- accum = sum_{i<j} exp(-max(d_i + d_j - 2 g_ij inv_i inv_j, 0)) ----
__global__ void k_expsum(const float* __restrict__ pbuf, const float* __restrict__ inv_norm,
                         const float* __restrict__ diag, float* __restrict__ accum) {
  const int gid = blockIdx.x * 256 + threadIdx.x;
  const int e0 = gid * 4;
  const int i  = e0 >> 10;
  const int j0 = e0 & 1023;
  const int ti = i >> 8, tj = j0 >> 8;
  float s = 0.f;
  if (tj >= ti && j0 + 3 > i) {
    const int t = tile_id(ti, tj);
    const int off = (i & 255) * 256 + (j0 & 255);
    float gx = 0.f, gy = 0.f, gz = 0.f, gw = 0.f;
    for (int c = 0; c < NCHUNK; ++c) {
      const float4 v = *(const float4*)(pbuf + (size_t)(t * NCHUNK + c) * 65536 + off);
      gx += v.x; gy += v.y; gz += v.z; gw += v.w;
    }
    const float wi = inv_norm[i];
    const float di = diag[i];
    const float4 wj = *(const float4*)(inv_norm + j0);
    const float4 dj = *(const float4*)(diag + j0);
    float gn, d2;
    gn = gx * wi * wj.x; d2 = fmaxf(di + dj.x - 2.f * gn, 0.f); if (i < j0 + 0) s += expf(-d2);
    gn = gy * wi * wj.y; d2 = fmaxf(di + dj.y - 2.f * gn, 0.f); if (i < j0 + 1) s += expf(-d2);
    gn = gz * wi * wj.z; d2 = fmaxf(di + dj.z - 2.f * gn, 0.f); if (i < j0 + 2) s += expf(-d2);
    gn = gw * wi * wj.w; d2 = fmaxf(di + dj.w - 2.f * gn, 0.f); if (i < j0 + 3) s += expf(-d2);
  }
  for (int off = 32; off; off >>= 1) s += __shfl_down(s, off, 64);
  __shared__ float part[4];
  const int lane = threadIdx.x & 63, w = threadIdx.x >> 6;
  if (lane == 0) part[w] = s;
  __syncthreads();
  if (threadIdx.x == 0) atomicAdd(accum, part[0] + part[1] + part[2] + part[3]);
}

__global__ void k_final(const float* __restrict__ accum, float* __restrict__ out) {
  const float n_pairs = (float)NROWS * (float)(NROWS - 1) * 0.5f;
  out[0] = 0.25f * logf(accum[0] / n_pairs);
}

extern "C" void kernel_launch(void* const* d_in, const int* in_sizes, int n_in,
                              void* d_out, int out_size, void* d_ws, size_t ws_size,
                              hipStream_t stream) {
  const float* z = (const float*)d_in[0];
  float* out = (float*)d_out;
  char* ws = (char*)d_ws;

  // layout: inv_norm 4KB | diag 4KB | accum | ... | pbuf 62.5MB | zb(fp8) 64MB
  float*    inv_norm = (float*)(ws);
  float*    diag     = (float*)(ws + 4096);
  float*    accum    = (float*)(ws + 8192);
  float*    pbuf     = (float*)(ws + 65536);
  uint32_t* zq       = (uint32_t*)(ws + 65536 + (size_t)PARTN * 65536 * sizeof(float));

  hipMemsetAsync(accum, 0, sizeof(float), stream);

  k_prep<<<NROWS, 256, 0, stream>>>(z, zq, inv_norm);

  hipFuncSetAttribute(reinterpret_cast<const void*>(&k_gram8),
                      hipFuncAttributeMaxDynamicSharedMemorySize, 131072);
  k_gram8<<<PARTN, 512, 131072, stream>>>((const unsigned char*)zq, pbuf);

  k_diag<<<NROWS / 256, 256, 0, stream>>>(pbuf, inv_norm, diag);
  k_expsum<<<(NROWS * NROWS / 4) / 256, 256, 0, stream>>>(pbuf, inv_norm, diag, accum);
  k_final<<<1, 1, 0, stream>>>(accum, out);
}

// Round 13
// 152.479 us; speedup vs baseline: 1.6762x; 1.1750x over previous
//
#include <hip/hip_runtime.h>
#include <hip/hip_bf16.h>
#include <stdint.h>

// DispersiveLoss: B=1024 rows, D=65536.
// R13: MX-scaled 32x32x64 f8f6f4 Gram (scales pinned to 1.0). R8-R12
// showed per-K-elem time invariant under byte-halving but tied to the
// ds_read INSTRUCTION count; the 32B/lane contiguous-k fragment of the
// scaled MFMA lets frags load as b128 pairs -> 24 b128/K-tile(128), half
// of R12's 48 b64 -- and the scaled MFMA rate is 2.14x plain fp8.
// Staging (gload_lds, XOR involution, vOff), 3-barrier schedule,
// vmcnt(6) ledger, 250-block XCD-grouped decomposition = R12 unchanged.

#define NROWS 1024
#define KDIM  65536           // elements per row (= fp8 bytes per row)
#define NCHUNK 25             // K-chunks per tile
#define PARTN  250            // 10 tiles * 25 chunks

typedef __attribute__((ext_vector_type(4)))  int   i32x4;
typedef __attribute__((ext_vector_type(8)))  int   i32x8;
typedef __attribute__((ext_vector_type(16))) float f32x16;

#define AS1 __attribute__((address_space(1)))
#define AS3 __attribute__((address_space(3)))

// scales = 0x7F (E8M0 exponent 127 -> 2^0 = 1.0); cbsz=0/blgp=0 -> FP8 e4m3
#define MFMA_SC(a, b, c) \
  __builtin_amdgcn_mfma_scale_f32_32x32x64_f8f6f4((a), (b), (c), 0, 0, \
      0, 0x7F7F7F7F, 0, 0x7F7F7F7F)

// ---- fused: row sum-of-squares -> inv_norm, plus fp32 -> fp8 e4m3 cast ----
__global__ void k_prep(const float* __restrict__ z, uint32_t* __restrict__ zq,
                       float* __restrict__ inv_norm) {
  const int row = blockIdx.x;
  const float4* zr = (const float4*)(z + (size_t)row * KDIM);
  uint32_t* qr = zq + (size_t)row * (KDIM / 4);
  float ss = 0.f;
  for (int i = threadIdx.x; i < KDIM / 4; i += blockDim.x) {
    const float4 v = zr[i];
    ss += v.x * v.x + v.y * v.y + v.z * v.z + v.w * v.w;
    int p = __builtin_amdgcn_cvt_pk_fp8_f32(v.x, v.y, 0, false);   // bytes 0,1
    p     = __builtin_amdgcn_cvt_pk_fp8_f32(v.z, v.w, p, true);    // bytes 2,3
    qr[i] = (uint32_t)p;
  }
  for (int off = 32; off; off >>= 1) ss += __shfl_down(ss, off, 64);
  __shared__ float part[4];
  const int lane = threadIdx.x & 63, w = threadIdx.x >> 6;
  if (lane == 0) part[w] = ss;
  __syncthreads();
  if (threadIdx.x == 0) {
    const float t = part[0] + part[1] + part[2] + part[3];
    inv_norm[row] = 1.f / fmaxf(sqrtf(t), 1e-12f);
  }
}

// ---- 256^2 fp8 Gram via mfma_scale 32x32x64: BK=128, A+B in LDS (128KB) ----
__global__
__attribute__((amdgpu_flat_work_group_size(512, 512), amdgpu_waves_per_eu(2, 2)))
void k_gram8(const unsigned char* __restrict__ zb, float* __restrict__ pbuf) {
  extern __shared__ char smem[];
  const int tid  = threadIdx.x;
  const int lane = tid & 63;
  const int wid  = tid >> 6;
  const int wr   = wid >> 2;     // 0..1  (M half: 128 rows)
  const int wc   = wid & 3;      // 0..3  (N quarter: 64 cols)

  // bijective XCD swizzle inverse (n=250, q=31, r=2)
  const int d   = blockIdx.x;
  const int xcd = d & 7, idx = d >> 3;
  const int l   = (xcd < 2) ? xcd * 32 + idx : 64 + (xcd - 2) * 31 + idx;
  const int kc   = l / 10;        // 0..24
  const int tile = l - kc * 10;   // 0..9
  // 512 K-tiles(128B) per tile column: first 12 chunks take 21, rest 20
  const int kts  = (kc < 12) ? kc * 21 : 20 * kc + 12;
  const int cnt  = (kc < 12) ? 21 : 20;
  const int pidx = tile * NCHUNK + kc;

  const int tm = (tile < 4) ? 0 : (tile < 7) ? 1 : (tile < 9) ? 2 : 3;
  const int tbase = 4 * tm - ((tm * (tm - 1)) >> 1);
  const int tn = tile - tbase + tm;

  // staging per-thread constant (pre-swizzled source; linear LDS dest)
  const uint32_t Pt   = (uint32_t)tid * 16u;
  const uint32_t Lt   = Pt ^ (((Pt >> 7) & 7u) << 4);
  const uint32_t vOff = (Lt >> 7) * (uint32_t)KDIM + (Lt & 127u);

  // frag b128 address regs. Lane's 32 k-bytes: col = kk64*64 + (lane>>5)*32,
  // stored at s = col ^ ((row&7)<<4); row = 32-mult + (lane&31) so
  // row&7 == lane&7. Second b128 of a frag at s ^ 16 (bit4 pre-add is 0).
  const uint32_t mask = ((uint32_t)lane & 7u) << 4;
  const uint32_t rowB = ((uint32_t)lane & 31u) * 128u;
  const uint32_t h5   = ((uint32_t)lane >> 5) * 32u;
  uint32_t vA[2], vAx[2], vB[2], vBx[2];
#pragma unroll
  for (int kk = 0; kk < 2; kk++) {
    const uint32_t sw = ((uint32_t)(kk * 64) + h5) ^ mask;
    vA[kk]  = (uint32_t)wr * 16384u + rowB + sw;
    vAx[kk] = vA[kk] ^ 16u;
    vB[kk]  = 65536u + (uint32_t)(wc >> 1) * 16384u + (uint32_t)(wc & 1) * 8192u
            + rowB + sw;
    vBx[kk] = vB[kk] ^ 16u;
  }

  const char* zbC = (const char*)zb;

  // panel row-byte bases (halves); rows are KDIM bytes (fp8)
  const uint32_t gA0 = (uint32_t)(tm * 256) * (uint32_t)KDIM;
  const uint32_t gA1 = gA0 + 128u * (uint32_t)KDIM;
  const uint32_t gB0 = (uint32_t)(tn * 256) * (uint32_t)KDIM;
  const uint32_t gB1 = gB0 + 128u * (uint32_t)KDIM;

  // stage one 128x128B half-tile (16 KB): 2 x global_load_lds(16B)/thread
  auto stage_half = [&](uint32_t gRowByte, uint32_t ldsHalfBase, int ktAbs) {
    const uint32_t g0 = gRowByte + (uint32_t)ktAbs * 128u;
#pragma unroll
    for (int q = 0; q < 2; q++) {
      __builtin_amdgcn_global_load_lds(
          (const AS1 void*)(zbC + (g0 + (uint32_t)q * (64u * (uint32_t)KDIM) + vOff)),
          (AS3 void*)(smem + (ldsHalfBase + (uint32_t)q * 8192u + Pt)), 16, 0, 0);
    }
  };

  // read one 32-row x 64-k fragment (two b128) at frag row-offset fi*32 rows
  auto rdf = [&](uint32_t base, uint32_t basex, int fi) -> i32x8 {
    const i32x4 lo = *(const i32x4*)(smem + (base  + (uint32_t)(fi * 4096)));
    const i32x4 hi = *(const i32x4*)(smem + (basex + (uint32_t)(fi * 4096)));
    return __builtin_shufflevector(lo, hi, 0, 1, 2, 3, 4, 5, 6, 7);
  };

  f32x16 acc[4][2];   // [mi 32-row frag][ni 32-col frag]
#pragma unroll
  for (int m = 0; m < 4; m++)
#pragma unroll
    for (int n = 0; n < 2; n++)
#pragma unroll
      for (int r = 0; r < 16; r++) acc[m][n][r] = 0.f;

  // prologue: 4 halves of K-tile kts -> buf0; B0,B1,A0 of kts+1 -> buf1
  stage_half(gB0, 65536u,           kts);
  stage_half(gB1, 65536u + 16384u,  kts);
  stage_half(gA0, 0u,               kts);
  stage_half(gA1, 16384u,           kts);
  stage_half(gB0, 65536u + 32768u,           kts + 1);
  stage_half(gB1, 65536u + 32768u + 16384u,  kts + 1);
  stage_half(gA0, 32768u,                    kts + 1);
  asm volatile("s_waitcnt vmcnt(6)" ::: "memory");  // K-tile kts fully landed
  __builtin_amdgcn_s_barrier();

  i32x8 aF[2][2], bF[2][2];
  for (int T = 0; T < cnt; ++T) {
    const uint32_t cur  = (uint32_t)(T & 1) * 32768u;
    const uint32_t idle = cur ^ 32768u;
    const bool stA = (T + 1 < cnt);
    const bool stB = (T + 2 < cnt);
    const int ktA = kts + T + 1;
    const int ktB = kts + T + 2;

    // ---- P01: stage A1(T+1->idle); read all B (8 b128) + A m0-1 (8 b128);
    //          MFMA m0-1 x n0-1 x kk0-1 (8) ----
    {
      if (stA) stage_half(gA1, idle + 16384u, ktA);
#pragma unroll
      for (int n = 0; n < 2; n++)
#pragma unroll
        for (int kk = 0; kk < 2; kk++) bF[n][kk] = rdf(vB[kk], vBx[kk], n);
#pragma unroll
      for (int m = 0; m < 2; m++)
#pragma unroll
        for (int kk = 0; kk < 2; kk++) aF[m][kk] = rdf(vA[kk], vAx[kk], m);
      __builtin_amdgcn_s_setprio(1);
#pragma unroll
      for (int m = 0; m < 2; m++)
#pragma unroll
        for (int n = 0; n < 2; n++)
#pragma unroll
          for (int kk = 0; kk < 2; kk++)
            acc[m][n] = MFMA_SC(aF[m][kk], bF[n][kk], acc[m][n]);
      __builtin_amdgcn_s_setprio(0);
      __builtin_amdgcn_s_barrier();   // B fully read -> B0 overwritable
    }

    // ---- P2: stage B0(T+2->cur); read A m2-3; MFMA m2 x n0-1 (4) ----
    {
      if (stB) stage_half(gB0, 65536u + cur, ktB);
#pragma unroll
      for (int m = 0; m < 2; m++)
#pragma unroll
        for (int kk = 0; kk < 2; kk++) aF[m][kk] = rdf(vA[kk], vAx[kk], m + 2);
      __builtin_amdgcn_s_setprio(1);
#pragma unroll
      for (int n = 0; n < 2; n++)
#pragma unroll
        for (int kk = 0; kk < 2; kk++)
          acc[2][n] = MFMA_SC(aF[0][kk], bF[n][kk], acc[2][n]);
      __builtin_amdgcn_s_setprio(0);
      __builtin_amdgcn_s_barrier();   // cur-A reads done -> A0/B1 overwritable
    }

    // ---- P3: stage B1+A0(T+2->cur); MFMA m3 x n0-1 (4); vmcnt(6) ----
    {
      if (stB) {
        stage_half(gB1, 65536u + cur + 16384u, ktB);
        stage_half(gA0, cur,                   ktB);
      }
      __builtin_amdgcn_s_setprio(1);
#pragma unroll
      for (int n = 0; n < 2; n++)
#pragma unroll
        for (int kk = 0; kk < 2; kk++)
          acc[3][n] = MFMA_SC(aF[1][kk], bF[n][kk], acc[3][n]);
      __builtin_amdgcn_s_setprio(0);
      // vmcnt(6): drains T+1's 4 halves; leaves T+2's 6 loads in flight.
      if (stB) { asm volatile("s_waitcnt vmcnt(6)" ::: "memory"); }
      else     { asm volatile("s_waitcnt vmcnt(0)" ::: "memory"); }
      __builtin_amdgcn_s_barrier();
#pragma unroll
      for (int kk = 0; kk < 2; kk++) {
        vA[kk] ^= 32768u; vAx[kk] ^= 32768u; vB[kk] ^= 32768u; vBx[kk] ^= 32768u;
      }
    }
  }

  // epilogue: 32x32 C/D layout (m74/m101, dtype-independent):
  // col = lane&31, row = (reg&3) + 8*(reg>>2) + 4*(lane>>5)
  float* outp = pbuf + (size_t)pidx * 65536;
  const int c0 = wc * 64 + (lane & 31);
  const int r0 = wr * 128 + ((lane >> 5) << 2);
#pragma unroll
  for (int m = 0; m < 4; m++)
#pragma unroll
    for (int n = 0; n < 2; n++)
#pragma unroll
      for (int r = 0; r < 16; r++) {
        const int R = r0 + m * 32 + (r & 3) + ((r >> 2) << 3);
        const int C = c0 + n * 32;
        outp[(size_t)R * 256 + C] = acc[m][n][r];
      }
}

// helpers: tile id from (ti<=tj)
__device__ __forceinline__ int tile_id(int ti, int tj) {
  return 4 * ti - ((ti * (ti - 1)) >> 1) + (tj - ti);
}

// ---- diag_n[i] = g[i][i] * inv_i^2 ----
__global__ void k_diag(const float* __restrict__ pbuf, const float* __restrict__ inv_norm,
                       float* __restrict__ diag) {
  const int i = blockIdx.x * 256 + threadIdx.x;
  const int ti = i >> 8;
  const int t = tile_id(ti, ti);
  const int off = (i & 255) * 257;
  float s = 0.f;
  for (int c = 0; c < NCHUNK; ++c)
    s += pbuf[(size_t)(t * NCHUNK + c) * 65536 + off];
  const float w = inv_norm[i];
  diag[i] = s * w * w;
}

// ---- accum = sum_{i<j} exp(-max(d_i + d_j - 2 g_ij inv_i inv_j, 0)) ----
__global__ void k_expsum(const float* __restrict__ pbuf, const float* __restrict__ inv_norm,
                         const float* __restrict__ diag, float* __restrict__ accum) {
  const int gid = blockIdx.x * 256 + threadIdx.x;
  const int e0 = gid * 4;
  const int i  = e0 >> 10;
  const int j0 = e0 & 1023;
  const int ti = i >> 8, tj = j0 >> 8;
  float s = 0.f;
  if (tj >= ti && j0 + 3 > i) {
    const int t = tile_id(ti, tj);
    const int off = (i & 255) * 256 + (j0 & 255);
    float gx = 0.f, gy = 0.f, gz = 0.f, gw = 0.f;
    for (int c = 0; c < NCHUNK; ++c) {
      const float4 v = *(const float4*)(pbuf + (size_t)(t * NCHUNK + c) * 65536 + off);
      gx += v.x; gy += v.y; gz += v.z; gw += v.w;
    }
    const float wi = inv_norm[i];
    const float di = diag[i];
    const float4 wj = *(const float4*)(inv_norm + j0);
    const float4 dj = *(const float4*)(diag + j0);
    float gn, d2;
    gn = gx * wi * wj.x; d2 = fmaxf(di + dj.x - 2.f * gn, 0.f); if (i < j0 + 0) s += expf(-d2);
    gn = gy * wi * wj.y; d2 = fmaxf(di + dj.y - 2.f * gn, 0.f); if (i < j0 + 1) s += expf(-d2);
    gn = gz * wi * wj.z; d2 = fmaxf(di + dj.z - 2.f * gn, 0.f); if (i < j0 + 2) s += expf(-d2);
    gn = gw * wi * wj.w; d2 = fmaxf(di + dj.w - 2.f * gn, 0.f); if (i < j0 + 3) s += expf(-d2);
  }
  for (int off = 32; off; off >>= 1) s += __shfl_down(s, off, 64);
  __shared__ float part[4];
  const int lane = threadIdx.x & 63, w = threadIdx.x >> 6;
  if (lane == 0) part[w] = s;
  __syncthreads();
  if (threadIdx.x == 0) atomicAdd(accum, part[0] + part[1] + part[2] + part[3]);
}

__global__ void k_final(const float* __restrict__ accum, float* __restrict__ out) {
  const float n_pairs = (float)NROWS * (float)(NROWS - 1) * 0.5f;
  out[0] = 0.25f * logf(accum[0] / n_pairs);
}

extern "C" void kernel_launch(void* const* d_in, const int* in_sizes, int n_in,
                              void* d_out, int out_size, void* d_ws, size_t ws_size,
                              hipStream_t stream) {
  const float* z = (const float*)d_in[0];
  float* out = (float*)d_out;
  char* ws = (char*)d_ws;

  // layout: inv_norm 4KB | diag 4KB | accum | ... | pbuf 62.5MB | zb(fp8) 64MB
  float*    inv_norm = (float*)(ws);
  float*    diag     = (float*)(ws + 4096);
  float*    accum    = (float*)(ws + 8192);
  float*    pbuf     = (float*)(ws + 65536);
  uint32_t* zq       = (uint32_t*)(ws + 65536 + (size_t)PARTN * 65536 * sizeof(float));

  hipMemsetAsync(accum, 0, sizeof(float), stream);

  k_prep<<<NROWS, 256, 0, stream>>>(z, zq, inv_norm);

  hipFuncSetAttribute(reinterpret_cast<const void*>(&k_gram8),
                      hipFuncAttributeMaxDynamicSharedMemorySize, 131072);
  k_gram8<<<PARTN, 512, 131072, stream>>>((const unsigned char*)zq, pbuf);

  k_diag<<<NROWS / 256, 256, 0, stream>>>(pbuf, inv_norm, diag);
  k_expsum<<<(NROWS * NROWS / 4) / 256, 256, 0, stream>>>(pbuf, inv_norm, diag, accum);
  k_final<<<1, 1, 0, stream>>>(accum, out);
}

// Round 14
// 139.234 us; speedup vs baseline: 1.8357x; 1.0951x over previous
//
#include <hip/hip_runtime.h>
#include <hip/hip_bf16.h>
#include <stdint.h>

// DispersiveLoss: B=1024 rows, D=65536.
// R14: cross-block overlap. R8-R13 ran 1 block/CU with 8 barrier-locked
// waves -> every phase tail (LDS drain, vmcnt, barrier) was dead on both
// pipes. Now: 128^2 tiles, 64 KB LDS, 256 thr (4 waves) -> 2 blocks/CU;
// one block's compute covers the other's stalls (m114 mechanism).
// Single-barrier K-tile loop (clean dbuf, no same-buf overwrites):
//   { stage A,B(T+1)->idle; read 16 b128; 8 MX-MFMA; vmcnt(0); bar }
// MX-scaled 32x32x64 fp8 (scales=1.0), XOR-involution swizzle, 504
// blocks = 36 upper-tri tiles x 14 K-chunks = 8 XCDs x 63 (L2-grouped).

#define NROWS 1024
#define KDIM  65536           // elements per row (= fp8 bytes per row)
#define NCHUNK 14             // K-chunks per tile
#define NTILE  36             // 8x8 upper-tri tiles
#define PARTN  504            // 36 * 14

typedef __attribute__((ext_vector_type(4)))  int   i32x4;
typedef __attribute__((ext_vector_type(8)))  int   i32x8;
typedef __attribute__((ext_vector_type(16))) float f32x16;

#define AS1 __attribute__((address_space(1)))
#define AS3 __attribute__((address_space(3)))

// scales = 0x7F (E8M0 -> 2^0 = 1.0); cbsz=0/blgp=0 -> FP8 e4m3
#define MFMA_SC(a, b, c) \
  __builtin_amdgcn_mfma_scale_f32_32x32x64_f8f6f4((a), (b), (c), 0, 0, \
      0, 0x7F7F7F7F, 0, 0x7F7F7F7F)

// ---- fused: row sum-of-squares -> inv_norm, plus fp32 -> fp8 e4m3 cast ----
__global__ void k_prep(const float* __restrict__ z, uint32_t* __restrict__ zq,
                       float* __restrict__ inv_norm) {
  const int row = blockIdx.x;
  const float4* zr = (const float4*)(z + (size_t)row * KDIM);
  uint32_t* qr = zq + (size_t)row * (KDIM / 4);
  float ss = 0.f;
  for (int i = threadIdx.x; i < KDIM / 4; i += blockDim.x) {
    const float4 v = zr[i];
    ss += v.x * v.x + v.y * v.y + v.z * v.z + v.w * v.w;
    int p = __builtin_amdgcn_cvt_pk_fp8_f32(v.x, v.y, 0, false);   // bytes 0,1
    p     = __builtin_amdgcn_cvt_pk_fp8_f32(v.z, v.w, p, true);    // bytes 2,3
    qr[i] = (uint32_t)p;
  }
  for (int off = 32; off; off >>= 1) ss += __shfl_down(ss, off, 64);
  __shared__ float part[4];
  const int lane = threadIdx.x & 63, w = threadIdx.x >> 6;
  if (lane == 0) part[w] = ss;
  __syncthreads();
  if (threadIdx.x == 0) {
    const float t = part[0] + part[1] + part[2] + part[3];
    inv_norm[row] = 1.f / fmaxf(sqrtf(t), 1e-12f);
  }
}

// ---- 128^2 fp8 Gram via mfma_scale 32x32x64: BK=128, 64 KB LDS dbuf ----
// LDS: A[buf] = buf*16384 ; B[buf] = 32768 + buf*16384 (16 KB panels).
// Swizzle within a panel (128 rows x 128 B): P = L ^ (((L>>7)&7)<<4).
__global__
__attribute__((amdgpu_flat_work_group_size(256, 256), amdgpu_waves_per_eu(2, 2)))
void k_gram8(const unsigned char* __restrict__ zb, float* __restrict__ pbuf) {
  extern __shared__ char smem[];
  const int tid  = threadIdx.x;
  const int lane = tid & 63;
  const int wid  = tid >> 6;     // 0..3
  const int wr   = wid >> 1;     // 0..1  (M half: 64 rows)
  const int wc   = wid & 1;      // 0..1  (N half: 64 cols)

  // XCD grouping: 504 = 8 * 63 exactly; l = xcd*63 + idx
  const int d = blockIdx.x;
  const int l = (d & 7) * 63 + (d >> 3);
  const int kc   = l / NTILE;     // 0..13
  const int tile = l - kc * NTILE;
  // 512 K-tiles(128B) per tile: first 8 chunks take 37, rest 36
  const int kts = (kc < 8) ? kc * 37 : 296 + (kc - 8) * 36;
  const int cnt = (kc < 8) ? 37 : 36;
  const int pidx = l;

  // tile -> (tm, tn) in 8x8 upper-tri (row-major enumeration)
  int tm = 0, rr = tile;
  while (rr >= 8 - tm) { rr -= 8 - tm; ++tm; }
  const int tn = tm + rr;

  // staging per-thread constant (pre-swizzled source; linear LDS dest)
  const uint32_t Pt   = (uint32_t)tid * 16u;                 // 0..4080
  const uint32_t Lt   = Pt ^ (((Pt >> 7) & 7u) << 4);
  const uint32_t vOff = (Lt >> 7) * (uint32_t)KDIM + (Lt & 127u);

  // frag b128 address regs: addr = (fragrow0 + lane&31)*128 + sw(kk), where
  // sw = (kk*64 + (lane>>5)*32) ^ ((lane&7)<<4); second b128 at ^16;
  // m/n frag offset = +4096 (32 rows); buf toggle = ^16384.
  const uint32_t mask = ((uint32_t)lane & 7u) << 4;
  const uint32_t rA = ((uint32_t)(wr * 64) + ((uint32_t)lane & 31u)) * 128u;
  const uint32_t rB = ((uint32_t)(wc * 64) + ((uint32_t)lane & 31u)) * 128u;
  const uint32_t h5 = ((uint32_t)lane >> 5) * 32u;
  uint32_t vA[2], vAx[2], vB[2], vBx[2];
#pragma unroll
  for (int kk = 0; kk < 2; kk++) {
    const uint32_t sw = ((uint32_t)(kk * 64) + h5) ^ mask;
    vA[kk]  = rA + sw;
    vAx[kk] = vA[kk] ^ 16u;
    vB[kk]  = 32768u + rB + sw;
    vBx[kk] = vB[kk] ^ 16u;
  }

  const char* zbC = (const char*)zb;
  const uint32_t gA = (uint32_t)(tm * 128) * (uint32_t)KDIM;
  const uint32_t gB = (uint32_t)(tn * 128) * (uint32_t)KDIM;

  // stage one 128x128B panel (16 KB): 4 x global_load_lds(16B)/thread
  auto stage_panel = [&](uint32_t gRowByte, uint32_t ldsBase, int ktAbs) {
    const uint32_t g0 = gRowByte + (uint32_t)ktAbs * 128u;
#pragma unroll
    for (int q = 0; q < 4; q++) {
      __builtin_amdgcn_global_load_lds(
          (const AS1 void*)(zbC + (g0 + (uint32_t)q * (32u * (uint32_t)KDIM) + vOff)),
          (AS3 void*)(smem + (ldsBase + (uint32_t)q * 4096u + Pt)), 16, 0, 0);
    }
  };

  // read one 32-row x 64-k fragment (two b128) at frag offset fi*4096
  auto rdf = [&](uint32_t base, uint32_t basex, int fi) -> i32x8 {
    const i32x4 lo = *(const i32x4*)(smem + (base  + (uint32_t)(fi * 4096)));
    const i32x4 hi = *(const i32x4*)(smem + (basex + (uint32_t)(fi * 4096)));
    return __builtin_shufflevector(lo, hi, 0, 1, 2, 3, 4, 5, 6, 7);
  };

  f32x16 acc[2][2];
#pragma unroll
  for (int m = 0; m < 2; m++)
#pragma unroll
    for (int n = 0; n < 2; n++)
#pragma unroll
      for (int r = 0; r < 16; r++) acc[m][n][r] = 0.f;

  // prologue: A(kts), B(kts) -> buf0
  stage_panel(gA, 0u,      kts);
  stage_panel(gB, 32768u,  kts);
  asm volatile("s_waitcnt vmcnt(0)" ::: "memory");
  __builtin_amdgcn_s_barrier();
  asm volatile("" ::: "memory");

  i32x8 aF[2][2], bF[2][2];
  for (int T = 0; T < cnt; ++T) {
    const uint32_t idle = (uint32_t)((T + 1) & 1) * 16384u;
    const bool st = (T + 1 < cnt);

    // stage next tile into idle buf (disjoint from cur -> no race)
    if (st) {
      stage_panel(gA, idle,           kts + T + 1);
      stage_panel(gB, 32768u + idle,  kts + T + 1);
    }
    // read all 16 b128 + 8 MFMA in ONE region: compiler interleaves
    // counted lgkmcnt so LDS service overlaps the MFMA cluster; the
    // co-resident block covers the tail.
#pragma unroll
    for (int kk = 0; kk < 2; kk++) {
#pragma unroll
      for (int m = 0; m < 2; m++) aF[m][kk] = rdf(vA[kk], vAx[kk], m);
#pragma unroll
      for (int n = 0; n < 2; n++) bF[n][kk] = rdf(vB[kk], vBx[kk], n);
    }
    __builtin_amdgcn_s_setprio(1);
#pragma unroll
    for (int m = 0; m < 2; m++)
#pragma unroll
      for (int n = 0; n < 2; n++)
#pragma unroll
        for (int kk = 0; kk < 2; kk++)
          acc[m][n] = MFMA_SC(aF[m][kk], bF[n][kk], acc[m][n]);
    __builtin_amdgcn_s_setprio(0);
    // drain T+1's loads (8) so next iteration may read them
    asm volatile("s_waitcnt vmcnt(0)" ::: "memory");
    __builtin_amdgcn_s_barrier();
    asm volatile("" ::: "memory");
#pragma unroll
    for (int kk = 0; kk < 2; kk++) {
      vA[kk] ^= 16384u; vAx[kk] ^= 16384u; vB[kk] ^= 16384u; vBx[kk] ^= 16384u;
    }
  }

  // epilogue: tile-local 128x128 partial (64 KB), non-atomic write
  // 32x32 C/D layout (m74/m101): col = lane&31, row = (r&3)+8*(r>>2)+4*(lane>>5)
  float* outp = pbuf + (size_t)pidx * 16384;
  const int r0 = wr * 64 + ((lane >> 5) << 2);
  const int c0 = wc * 64 + (lane & 31);
#pragma unroll
  for (int m = 0; m < 2; m++)
#pragma unroll
    for (int n = 0; n < 2; n++)
#pragma unroll
      for (int r = 0; r < 16; r++) {
        const int R = r0 + m * 32 + (r & 3) + ((r >> 2) << 3);
        const int C = c0 + n * 32;
        outp[(size_t)R * 128 + C] = acc[m][n][r];
      }
}

// helpers: tile id from (ti<=tj), 8x8 grid
__device__ __forceinline__ int tile_id(int ti, int tj) {
  return 8 * ti - ((ti * (ti - 1)) >> 1) + (tj - ti);
}

// ---- diag_n[i] = g[i][i] * inv_i^2 ----
__global__ void k_diag(const float* __restrict__ pbuf, const float* __restrict__ inv_norm,
                       float* __restrict__ diag) {
  const int i = blockIdx.x * 256 + threadIdx.x;
  const int ti = i >> 7;
  const int t = tile_id(ti, ti);
  const int off = (i & 127) * 129;
  float s = 0.f;
  for (int c = 0; c < NCHUNK; ++c)
    s += pbuf[(size_t)(c * NTILE + t) * 16384 + off];
  const float w = inv_norm[i];
  diag[i] = s * w * w;
}

// ---- accum = sum_{i<j} exp(-max(d_i + d_j - 2 g_ij inv_i inv_j, 0)) ----
__global__ void k_expsum(const float* __restrict__ pbuf, const float* __restrict__ inv_norm,
                         const float* __restrict__ diag, float* __restrict__ accum) {
  const int gid = blockIdx.x * 256 + threadIdx.x;
  const int e0 = gid * 4;
  const int i  = e0 >> 10;
  const int j0 = e0 & 1023;
  const int ti = i >> 7, tj = j0 >> 7;
  float s = 0.f;
  if (tj >= ti && j0 + 3 > i) {
    const int t = tile_id(ti, tj);
    const int off = (i & 127) * 128 + (j0 & 127);
    float gx = 0.f, gy = 0.f, gz = 0.f, gw = 0.f;
    for (int c = 0; c < NCHUNK; ++c) {
      const float4 v = *(const float4*)(pbuf + (size_t)(c * NTILE + t) * 16384 + off);
      gx += v.x; gy += v.y; gz += v.z; gw += v.w;
    }
    const float wi = inv_norm[i];
    const float di = diag[i];
    const float4 wj = *(const float4*)(inv_norm + j0);
    const float4 dj = *(const float4*)(diag + j0);
    float gn, d2;
    gn = gx * wi * wj.x; d2 = fmaxf(di + dj.x - 2.f * gn, 0.f); if (i < j0 + 0) s += expf(-d2);
    gn = gy * wi * wj.y; d2 = fmaxf(di + dj.y - 2.f * gn, 0.f); if (i < j0 + 1) s += expf(-d2);
    gn = gz * wi * wj.z; d2 = fmaxf(di + dj.z - 2.f * gn, 0.f); if (i < j0 + 2) s += expf(-d2);
    gn = gw * wi * wj.w; d2 = fmaxf(di + dj.w - 2.f * gn, 0.f); if (i < j0 + 3) s += expf(-d2);
  }
  for (int off = 32; off; off >>= 1) s += __shfl_down(s, off, 64);
  __shared__ float part[4];
  const int lane = threadIdx.x & 63, w = threadIdx.x >> 6;
  if (lane == 0) part[w] = s;
  __syncthreads();
  if (threadIdx.x == 0) atomicAdd(accum, part[0] + part[1] + part[2] + part[3]);
}

__global__ void k_final(const float* __restrict__ accum, float* __restrict__ out) {
  const float n_pairs = (float)NROWS * (float)(NROWS - 1) * 0.5f;
  out[0] = 0.25f * logf(accum[0] / n_pairs);
}

extern "C" void kernel_launch(void* const* d_in, const int* in_sizes, int n_in,
                              void* d_out, int out_size, void* d_ws, size_t ws_size,
                              hipStream_t stream) {
  const float* z = (const float*)d_in[0];
  float* out = (float*)d_out;
  char* ws = (char*)d_ws;

  // layout: inv_norm 4KB | diag 4KB | accum | ... | pbuf 33MB | zb(fp8) 64MB
  float*    inv_norm = (float*)(ws);
  float*    diag     = (float*)(ws + 4096);
  float*    accum    = (float*)(ws + 8192);
  float*    pbuf     = (float*)(ws + 65536);
  uint32_t* zq       = (uint32_t*)(ws + 65536 + (size_t)PARTN * 16384 * sizeof(float));

  hipMemsetAsync(accum, 0, sizeof(float), stream);

  k_prep<<<NROWS, 256, 0, stream>>>(z, zq, inv_norm);

  hipFuncSetAttribute(reinterpret_cast<const void*>(&k_gram8),
                      hipFuncAttributeMaxDynamicSharedMemorySize, 65536);
  k_gram8<<<PARTN, 256, 65536, stream>>>((const unsigned char*)zq, pbuf);

  k_diag<<<NROWS / 256, 256, 0, stream>>>(pbuf, inv_norm, diag);
  k_expsum<<<(NROWS * NROWS / 4) / 256, 256, 0, stream>>>(pbuf, inv_norm, diag, accum);
  k_final<<<1, 1, 0, stream>>>(accum, out);
}